// Round 9
// baseline (424.733 us; speedup 1.0000x reference)
//
#include <hip/hip_runtime.h>
#include <hip/hip_bf16.h>

#define N_NODES 100000
#define N_EDGES 1600000
#define LATENT 64
#define N_GRAPH 100
#define OUT_G 16
#define N_STEPS 3

// CSR-build geometry
#define NCHUNK 4
#define CHUNKN 25000            // nodes per chunk
#define CHUNKW 12500            // packed u16-pair words per chunk (50 KB LDS)
#define NSLICE 32
#define SLICE_E 50000           // edges per slice

#define POOL_PB 8               // stage-1 blocks per graph
#define COL_CAP (N_EDGES + 7 * N_NODES + 64)   // padded CSR capacity

using bf16 = __hip_bfloat16;
using bf16x8 = __attribute__((ext_vector_type(8))) short;
using f32x4  = __attribute__((ext_vector_type(4))) float;

__device__ __forceinline__ float blo(unsigned int u) {
    union { unsigned int i; float f; } v; v.i = u << 16; return v.f;
}
__device__ __forceinline__ float bhi(unsigned int u) {
    union { unsigned int i; float f; } v; v.i = u & 0xffff0000u; return v.f;
}
__device__ __forceinline__ float bf2f(short s) {
    union { unsigned int i; float f; } v; v.i = ((unsigned int)(unsigned short)s) << 16; return v.f;
}

// ---------------- K1: per-(chunk,slice) LDS histogram of one index array ------
__global__ __launch_bounds__(512) void csr_hist1(
    const int* __restrict__ idx, unsigned int* __restrict__ hist_g)
{
    __shared__ unsigned int hist[CHUNKW];   // 50 KB
    int c = blockIdx.x & (NCHUNK - 1), s = blockIdx.x >> 2;
    int t = threadIdx.x;
    for (int w = t; w < CHUNKW; w += 512) hist[w] = 0;
    __syncthreads();
    int base = s * SLICE_E;
    int lo = c * CHUNKN;
    for (int e = base + t; e < base + SLICE_E; e += 512) {
        unsigned int rl = (unsigned int)(idx[e] - lo);
        if (rl < CHUNKN) atomicAdd(&hist[rl >> 1], (rl & 1) ? 65536u : 1u);
    }
    __syncthreads();
    unsigned int* outp = hist_g + (size_t)blockIdx.x * CHUNKW;
    for (int w = t; w < CHUNKW; w += 512) outp[w] = hist[w];
}

// ------ K2: scan slice-partials -> offsets + padded cnt + real cnt + inv ------
__global__ __launch_bounds__(256) void csr_scan_blocks(
    const unsigned int* __restrict__ histR_g, const unsigned int* __restrict__ histS_g,
    unsigned short* __restrict__ blockoffR, int* __restrict__ cntPad,
    int* __restrict__ cntReal, float* __restrict__ inv_r, float* __restrict__ inv_s)
{
    int tid = blockIdx.x * blockDim.x + threadIdx.x;
    if (tid >= NCHUNK * CHUNKW) return;
    int c = tid / CHUNKW, w = tid - c * CHUNKW;
    int node = c * CHUNKN + 2 * w;
    unsigned int runLo = 0, runHi = 0;
#pragma unroll 8
    for (int s = 0; s < NSLICE; s++) {
        unsigned int v = histR_g[(size_t)(s * NCHUNK + c) * CHUNKW + w];
        *(unsigned int*)&blockoffR[(size_t)s * N_NODES + node] =
            (runLo & 0xffffu) | (runHi << 16);
        runLo += v & 0xffffu; runHi += v >> 16;
    }
    ((int2*)cntReal)[node >> 1] = make_int2((int)runLo, (int)runHi);
    ((int2*)cntPad)[node >> 1] =
        make_int2((int)((runLo + 7u) & ~7u), (int)((runHi + 7u) & ~7u));
    ((float2*)inv_r)[node >> 1] =
        make_float2(rsqrtf((float)(runLo + 1)), rsqrtf((float)(runHi + 1)));
    runLo = runHi = 0;
#pragma unroll 8
    for (int s = 0; s < NSLICE; s++) {
        unsigned int v = histS_g[(size_t)(s * NCHUNK + c) * CHUNKW + w];
        runLo += v & 0xffffu; runHi += v >> 16;
    }
    ((float2*)inv_s)[node >> 1] =
        make_float2(rsqrtf((float)(runLo + 1)), rsqrtf((float)(runHi + 1)));
}

// ---------------- exclusive scan of padded counts -> row_ptr ----------------
__global__ __launch_bounds__(256) void scan_blocksum(
    const int* __restrict__ cnt, int* __restrict__ partial)
{
    __shared__ int sred[256];
    int b = blockIdx.x, t = threadIdx.x;
    int base = b * 1024 + t * 4;
    int s = 0;
#pragma unroll
    for (int j = 0; j < 4; j++) {
        int i = base + j;
        s += (i < N_NODES) ? cnt[i] : 0;
    }
    sred[t] = s;
    __syncthreads();
    for (int off = 128; off > 0; off >>= 1) {
        if (t < off) sred[t] += sred[t + off];
        __syncthreads();
    }
    if (t == 0) partial[b] = sred[0];
}

__global__ __launch_bounds__(128) void scan_partials_par(int* partial, int nblk)
{
    __shared__ int lds[128];
    int t = threadIdx.x;
    int v = (t < nblk) ? partial[t] : 0;
    lds[t] = v;
    __syncthreads();
    for (int off = 1; off < 128; off <<= 1) {
        int add = (t >= off) ? lds[t - off] : 0;
        __syncthreads();
        lds[t] += add;
        __syncthreads();
    }
    if (t < nblk) partial[t] = lds[t] - v;   // exclusive
}

// scan_final also writes the pad slots of col (zero-row index N_NODES)
__global__ __launch_bounds__(256) void scan_final(
    const int* __restrict__ cnt, const int* __restrict__ cntReal,
    const int* __restrict__ partial, int* __restrict__ row_ptr,
    int* __restrict__ col)
{
    __shared__ int lds[256];
    int b = blockIdx.x, t = threadIdx.x;
    int base = b * 1024 + t * 4;
    int v[4]; int s = 0;
#pragma unroll
    for (int j = 0; j < 4; j++) {
        int i = base + j;
        v[j] = (i < N_NODES) ? cnt[i] : 0;
        s += v[j];
    }
    lds[t] = s;
    __syncthreads();
    for (int off = 1; off < 256; off <<= 1) {
        int add = (t >= off) ? lds[t - off] : 0;
        __syncthreads();
        lds[t] += add;
        __syncthreads();
    }
    int run = lds[t] - s + partial[b];
#pragma unroll
    for (int j = 0; j < 4; j++) {
        int i = base + j;
        if (i < N_NODES) {
            row_ptr[i] = run;
            int real = cntReal[i];
            for (int k = real; k < v[j]; k++) col[run + k] = N_NODES;
            run += v[j];
            if (i == N_NODES - 1) row_ptr[N_NODES] = run;
        }
    }
}

// ---------------- K3: scatter with LDS local ranks (no global atomics) --------
__global__ __launch_bounds__(512) void csr_scatter(
    const int* __restrict__ senders, const int* __restrict__ receivers,
    const int* __restrict__ row_ptr, const unsigned short* __restrict__ blockoffR,
    int* __restrict__ col)
{
    __shared__ unsigned int lrank[CHUNKW];   // 50 KB
    int c = blockIdx.x & (NCHUNK - 1), s = blockIdx.x >> 2;
    int t = threadIdx.x;
    for (int w = t; w < CHUNKW; w += 512) lrank[w] = 0;
    __syncthreads();
    int base = s * SLICE_E;
    int lo = c * CHUNKN;
    const unsigned short* boff = blockoffR + (size_t)s * N_NODES;
    for (int e = base + t; e < base + SLICE_E; e += 512) {
        int r  = receivers[e];
        int sd = senders[e];
        unsigned int rl = (unsigned int)(r - lo);
        if (rl < CHUNKN) {
            unsigned int old = atomicAdd(&lrank[rl >> 1], (rl & 1) ? 65536u : 1u);
            unsigned int lr = (rl & 1) ? (old >> 16) : (old & 0xffffu);
            col[row_ptr[r] + (int)boff[r] + (int)lr] = sd;
        }
    }
}

// ---------------- embed: xb = bf16(nodes @ W_embed + b_embed) + zero row ------
__global__ __launch_bounds__(256) void embed_kernel(
    const float* __restrict__ nodes, const float* __restrict__ We,
    const float* __restrict__ be, bf16* __restrict__ xb, bf16* __restrict__ h)
{
    int tid = blockIdx.x * blockDim.x + threadIdx.x;   // (node, col-chunk of 8)
    if (tid < 8) {   // zero row h[N_NODES] for padded-CSR gathers
        bf16x8 z = {};
        *(bf16x8*)&h[(size_t)N_NODES * 64 + tid * 8] = z;
    }
    if (tid >= N_NODES * 8) return;
    int i = tid >> 3, cc = tid & 7;
    float n0 = nodes[i * 3 + 0], n1 = nodes[i * 3 + 1], n2 = nodes[i * 3 + 2];
    union { bf16x8 v; bf16 h[8]; } pk;
#pragma unroll
    for (int k = 0; k < 8; k++) {
        int d = cc * 8 + k;
        float acc = be[d] + n0 * We[0 * 64 + d] + n1 * We[1 * 64 + d] + n2 * We[2 * 64 + d];
        pk.h[k] = __float2bfloat16(acc);
    }
    *(bf16x8*)&xb[(size_t)i * 64 + cc * 8] = pk.v;
}

// ---------------- W fragment pre-pack (f32 -> bf16, MFMA frag order) ----------
__global__ __launch_bounds__(256) void wfrag_kernel(
    const float* __restrict__ W0, const float* __restrict__ W1,
    bf16* __restrict__ frags)
{
    int tid = blockIdx.x * blockDim.x + threadIdx.x;
    if (tid >= 8192) return;
    int j    = tid & 7;
    int lane = (tid >> 3) & 63;
    int c    = (tid >> 9) & 1;
    int nt   = (tid >> 10) & 3;
    int L    = (tid >> 12) & 1;
    int g = lane >> 4, q = lane & 15;
    int k = c * 32 + g * 8 + j;
    int colIdx = nt * 16 + q;
    const float* W = L ? W1 : W0;
    frags[tid] = __float2bfloat16(W[k * 64 + colIdx]);
}

// ---------------- MFMA 2-layer MLP (+ inv_sqrt_s epilogue), bf16 ----------------
__global__ __launch_bounds__(256) void mlp_mfma(
    const bf16* __restrict__ xb, bf16* __restrict__ h,
    const bf16* __restrict__ wfrag,
    const float* __restrict__ b0, const float* __restrict__ b1,
    const float* __restrict__ inv_s)
{
    __shared__ char lds_raw[4][2048];
    int t = threadIdx.x;
    int w = t >> 6, lane = t & 63;
    int g = lane >> 4, q = lane & 15;
    char* myLds = lds_raw[w];

    bf16x8 wf[2][4][2];
#pragma unroll
    for (int L = 0; L < 2; L++)
#pragma unroll
        for (int nt = 0; nt < 4; nt++)
#pragma unroll
            for (int c = 0; c < 2; c++)
                wf[L][nt][c] = *(const bf16x8*)&wfrag[((((L * 4 + nt) * 2 + c) * 64) + lane) * 8];

    float bias0[4], bias1[4];
#pragma unroll
    for (int nt = 0; nt < 4; nt++) {
        bias0[nt] = b0[nt * 16 + q];
        bias1[nt] = b1[nt * 16 + q];
    }

    const int NTILES = N_NODES / 16;  // 6250
    for (int tile = blockIdx.x * 4 + w; tile < NTILES; tile += gridDim.x * 4) {
        int nodeBase = tile * 16;

        bf16x8 a0[2];
#pragma unroll
        for (int c = 0; c < 2; c++)
            a0[c] = *(const bf16x8*)&xb[(size_t)(nodeBase + q) * 64 + c * 32 + g * 8];

        f32x4 acc[4];
#pragma unroll
        for (int nt = 0; nt < 4; nt++) {
            acc[nt] = (f32x4){bias0[nt], bias0[nt], bias0[nt], bias0[nt]};
            acc[nt] = __builtin_amdgcn_mfma_f32_16x16x32_bf16(a0[0], wf[0][nt][0], acc[nt], 0, 0, 0);
            acc[nt] = __builtin_amdgcn_mfma_f32_16x16x32_bf16(a0[1], wf[0][nt][1], acc[nt], 0, 0, 0);
        }
#pragma unroll
        for (int nt = 0; nt < 4; nt++)
#pragma unroll
            for (int r = 0; r < 4; r++) {
                float v = fmaxf(acc[nt][r], 0.f);
                int node = g * 4 + r;
                int byte = ((node * 128 + (nt * 16 + q) * 2)) ^ ((node & 7) << 4);
                *(bf16*)(myLds + byte) = __float2bfloat16(v);
            }
        bf16x8 a1[2];
#pragma unroll
        for (int c = 0; c < 2; c++) {
            int byte = (q * 128 + c * 64 + g * 16) ^ ((q & 7) << 4);
            a1[c] = *(const bf16x8*)(myLds + byte);
        }

        f32x4 acc1[4];
#pragma unroll
        for (int nt = 0; nt < 4; nt++) {
            acc1[nt] = (f32x4){bias1[nt], bias1[nt], bias1[nt], bias1[nt]};
            acc1[nt] = __builtin_amdgcn_mfma_f32_16x16x32_bf16(a1[0], wf[1][nt][0], acc1[nt], 0, 0, 0);
            acc1[nt] = __builtin_amdgcn_mfma_f32_16x16x32_bf16(a1[1], wf[1][nt][1], acc1[nt], 0, 0, 0);
        }
        float is[4];
#pragma unroll
        for (int r = 0; r < 4; r++) is[r] = inv_s[nodeBase + g * 4 + r];
#pragma unroll
        for (int nt = 0; nt < 4; nt++)
#pragma unroll
            for (int r = 0; r < 4; r++) {
                float v = fmaxf(acc1[nt][r], 0.f) * is[r];
                int node = g * 4 + r;
                int byte = ((node * 128 + (nt * 16 + q) * 2)) ^ ((node & 7) << 4);
                *(bf16*)(myLds + byte) = __float2bfloat16(v);
            }
#pragma unroll
        for (int half = 0; half < 2; half++) {
            int byteL = lane * 32 + half * 16;
            int node = byteL >> 7;
            bf16x8 v = *(const bf16x8*)(myLds + (byteL ^ ((node & 7) << 4)));
            *(bf16x8*)&h[(size_t)nodeBase * 64 + lane * 16 + half * 8] = v;
        }
    }
}

// ------- gather-aggregate: padded rows, branch-free 8-edge loop + LN ----------
__global__ __launch_bounds__(256) void agg_ln_kernel(
    const bf16* __restrict__ h, bf16* __restrict__ xb,
    const int* __restrict__ row_ptr, const int* __restrict__ col,
    const float* __restrict__ inv_r,
    const float* __restrict__ ln_scale, const float* __restrict__ ln_bias)
{
    int t = threadIdx.x;
    int lane = t & 63;
    int sub = lane >> 5;          // which edge of the pair this half-wave handles
    int c = lane & 31;            // this lane covers columns 2c, 2c+1
    float2 lnsv = *(const float2*)&ln_scale[2 * c];
    float2 lnbv = *(const float2*)&ln_bias[2 * c];
    int gw = __builtin_amdgcn_readfirstlane((blockIdx.x * blockDim.x + t) >> 6);
    int nwaves = (gridDim.x * blockDim.x) >> 6;
    for (int i = gw; i < N_NODES; i += nwaves) {
        float a0 = 0.f, a1 = 0.f, b0 = 0.f, b1 = 0.f;
        // self edge (inv_s already folded into h); count once via sub==0
        unsigned int su = *(const unsigned int*)&h[(size_t)i * 64 + 2 * c];
        if (sub == 0) { a0 += blo(su); a1 += bhi(su); }
        int beg = row_ptr[i], end = row_ptr[i + 1];   // padded: (end-beg) % 8 == 0
        for (int e = beg; e < end; e += 8) {
            int r0 = col[e + 0 + sub];
            int r1 = col[e + 2 + sub];
            int r2 = col[e + 4 + sub];
            int r3 = col[e + 6 + sub];
            unsigned int u0 = *(const unsigned int*)&h[(size_t)r0 * 64 + 2 * c];
            unsigned int u1 = *(const unsigned int*)&h[(size_t)r1 * 64 + 2 * c];
            unsigned int u2 = *(const unsigned int*)&h[(size_t)r2 * 64 + 2 * c];
            unsigned int u3 = *(const unsigned int*)&h[(size_t)r3 * 64 + 2 * c];
            a0 += blo(u0) + blo(u1);
            a1 += bhi(u0) + bhi(u1);
            b0 += blo(u2) + blo(u3);
            b1 += bhi(u2) + bhi(u3);
        }
        a0 += b0; a1 += b1;
        // merge the two half-wave partial sums
        a0 += __shfl_xor(a0, 32);
        a1 += __shfl_xor(a1, 32);
        float ir = inv_r[i];
        unsigned int xu = *(const unsigned int*)&xb[(size_t)i * 64 + 2 * c];
        float y0 = a0 * ir + blo(xu);
        float y1 = a1 * ir + bhi(xu);
        // LayerNorm over 64 cols = 2 per lane x 32 lanes (duplicated across halves)
        float sum = y0 + y1;
#pragma unroll
        for (int m = 1; m < 32; m <<= 1) sum += __shfl_xor(sum, m);
        float mu = sum * (1.f / 64.f);
        float d0 = y0 - mu, d1 = y1 - mu;
        float vs = d0 * d0 + d1 * d1;
#pragma unroll
        for (int m = 1; m < 32; m <<= 1) vs += __shfl_xor(vs, m);
        float var = vs * (1.f / 64.f);
        float rr = rsqrtf(var + 1e-6f);
        float o0 = d0 * rr * lnsv.x + lnbv.x;
        float o1 = d1 * rr * lnsv.y + lnbv.y;
        if (sub == 0) {
            union { unsigned int u; bf16 h2[2]; } pk;
            pk.h2[0] = __float2bfloat16(o0);
            pk.h2[1] = __float2bfloat16(o1);
            *(unsigned int*)&xb[(size_t)i * 64 + 2 * c] = pk.u;
        }
    }
}

// ---------------- pool stage 1: partial sums, vectorized bf16x8 loads ---------
__global__ __launch_bounds__(256) void pool_stage1(
    const bf16* __restrict__ xb, const int* __restrict__ n_node,
    float* __restrict__ partialP)   // [N_GRAPH][POOL_PB][64]
{
    __shared__ float red[32][8][8];  // 8 KB
    int b = blockIdx.x;
    int g = b >> 3, sub = b & 7;
    int t = threadIdx.x;
    int start = 0;
    for (int j = 0; j < g; j++) start += n_node[j];
    int cnt = n_node[g];
    int jbeg = (int)(((long long)cnt * sub) / POOL_PB);
    int jend = (int)(((long long)cnt * (sub + 1)) / POOL_PB);
    int rg = t >> 3, cc = t & 7;
    float acc[8];
#pragma unroll
    for (int k = 0; k < 8; k++) acc[k] = 0.f;
    for (int j = jbeg + rg; j < jend; j += 32) {
        bf16x8 v = *(const bf16x8*)&xb[(size_t)(start + j) * 64 + cc * 8];
#pragma unroll
        for (int k = 0; k < 8; k++) acc[k] += bf2f(v[k]);
    }
#pragma unroll
    for (int k = 0; k < 8; k++) red[rg][cc][k] = acc[k];
    __syncthreads();
    if (t < 64) {
        float s = 0.f;
#pragma unroll 8
        for (int r = 0; r < 32; r++) s += red[r][t >> 3][t & 7];
        partialP[((size_t)g * POOL_PB + sub) * 64 + t] = s;
    }
}

// ---------------- pool stage 2: reduce partials + mean + decoder GEMV ---------
__global__ __launch_bounds__(64) void pool_stage2(
    const float* __restrict__ partialP, const int* __restrict__ n_node,
    const float* __restrict__ Wg, const float* __restrict__ bg,
    float* __restrict__ out)
{
    __shared__ float pd[64];
    int g = blockIdx.x;
    int t = threadIdx.x;
    float s = 0.f;
#pragma unroll
    for (int p = 0; p < POOL_PB; p++) s += partialP[((size_t)g * POOL_PB + p) * 64 + t];
    int cnt = n_node[g];
    pd[t] = s / fmaxf((float)cnt, 1.f);
    __syncthreads();
    if (t < OUT_G) {
        float v = bg[t];
#pragma unroll 16
        for (int dd = 0; dd < 64; dd++) v += pd[dd] * Wg[dd * OUT_G + t];
        out[g * OUT_G + t] = v;
    }
}

extern "C" void kernel_launch(void* const* d_in, const int* in_sizes, int n_in,
                              void* d_out, int out_size, void* d_ws, size_t ws_size,
                              hipStream_t stream) {
    const float* nodes    = (const float*)d_in[0];
    const int*   senders  = (const int*)d_in[1];
    const int*   receivers= (const int*)d_in[2];
    const int*   n_node   = (const int*)d_in[3];
    const float* W_embed  = (const float*)d_in[4];
    const float* b_embed  = (const float*)d_in[5];
    const float* W_mlp0   = (const float*)d_in[6];
    const float* b_mlp0   = (const float*)d_in[7];
    const float* W_mlp1   = (const float*)d_in[8];
    const float* b_mlp1   = (const float*)d_in[9];
    const float* ln_scale = (const float*)d_in[10];
    const float* ln_bias  = (const float*)d_in[11];
    const float* W_glob   = (const float*)d_in[12];
    const float* b_glob   = (const float*)d_in[13];
    float* out = (float*)d_out;

    // workspace layout (16B-aligned pieces)
    char* ws = (char*)d_ws;
    bf16*  xb     = (bf16*)ws;    ws += (size_t)N_NODES * 64 * 2;        // 12.8 MB
    bf16*  h      = (bf16*)ws;    ws += (size_t)(N_NODES + 1) * 64 * 2;  // 12.8 MB + zero row
    unsigned int* histS_g = (unsigned int*)ws; ws += (size_t)NSLICE * NCHUNK * CHUNKW * 4; // 6.4 MB
    float* inv_s  = (float*)ws;   ws += (size_t)N_NODES * 4;
    float* inv_r  = (float*)ws;   ws += (size_t)N_NODES * 4;
    int*   cntPad = (int*)ws;     ws += (size_t)N_NODES * 4;
    int*   cntReal= (int*)ws;     ws += (size_t)N_NODES * 4;
    int*   row_ptr= (int*)ws;     ws += (size_t)(N_NODES + 4) * 4;
    int*   col    = (int*)ws;     ws += (size_t)COL_CAP * 4;             // 9.2 MB
    int*   partial= (int*)ws;     ws += 256 * 4;
    bf16*  wfrag  = (bf16*)ws;    ws += 8192 * 2;
    float* partialP = (float*)ws; ws += (size_t)N_GRAPH * POOL_PB * 64 * 4;

    // CSR-build temporaries alias h/xb (dead until the step loop)
    unsigned int*   histR_g   = (unsigned int*)h;     // 6.4 MB, read before mlp writes h
    unsigned short* blockoffR = (unsigned short*)xb;  // 6.4 MB, read before embed writes xb

    const int nblk_scan = (N_NODES + 1023) / 1024;  // 98

    // ---- CSR build (no global atomics), padded rows ----
    csr_hist1<<<NSLICE * NCHUNK, 512, 0, stream>>>(receivers, histR_g);
    csr_hist1<<<NSLICE * NCHUNK, 512, 0, stream>>>(senders, histS_g);
    csr_scan_blocks<<<(NCHUNK * CHUNKW + 255) / 256, 256, 0, stream>>>(
        histR_g, histS_g, blockoffR, cntPad, cntReal, inv_r, inv_s);
    scan_blocksum<<<nblk_scan, 256, 0, stream>>>(cntPad, partial);
    scan_partials_par<<<1, 128, 0, stream>>>(partial, nblk_scan);
    scan_final<<<nblk_scan, 256, 0, stream>>>(cntPad, cntReal, partial, row_ptr, col);
    csr_scatter<<<NSLICE * NCHUNK, 512, 0, stream>>>(senders, receivers, row_ptr, blockoffR, col);

    // ---- embed (after CSR temporaries are dead) ----
    embed_kernel<<<(N_NODES * 8 + 255) / 256, 256, 0, stream>>>(nodes, W_embed, b_embed, xb, h);
    wfrag_kernel<<<32, 256, 0, stream>>>(W_mlp0, W_mlp1, wfrag);

    for (int step = 0; step < N_STEPS; ++step) {
        mlp_mfma<<<1563, 256, 0, stream>>>(xb, h, wfrag, b_mlp0, b_mlp1, inv_s);
        agg_ln_kernel<<<4096, 256, 0, stream>>>(h, xb, row_ptr, col, inv_r, ln_scale, ln_bias);
    }

    pool_stage1<<<N_GRAPH * POOL_PB, 256, 0, stream>>>(xb, n_node, partialP);
    pool_stage2<<<N_GRAPH, 64, 0, stream>>>(partialP, n_node, W_glob, b_glob, out);
}

// Round 10
// 375.033 us; speedup vs baseline: 1.1325x; 1.1325x over previous
//
#include <hip/hip_runtime.h>
#include <hip/hip_bf16.h>

#define N_NODES 100000
#define N_EDGES 1600000
#define LATENT 64
#define N_GRAPH 100
#define OUT_G 16
#define N_STEPS 3

// CSR-build geometry
#define NCHUNK 4
#define CHUNKN 25000            // nodes per chunk
#define CHUNKW 12500            // packed u16-pair words per chunk (50 KB LDS)
#define NSLICE 64
#define SLICE_E 25000           // edges per slice

#define POOL_PB 8               // stage-1 blocks per graph
#define COL_CAP (N_EDGES + 7 * N_NODES + 64)   // padded CSR capacity

using bf16 = __hip_bfloat16;
using bf16x8 = __attribute__((ext_vector_type(8))) short;
using f32x4  = __attribute__((ext_vector_type(4))) float;

__device__ __forceinline__ float blo(unsigned int u) {
    union { unsigned int i; float f; } v; v.i = u << 16; return v.f;
}
__device__ __forceinline__ float bhi(unsigned int u) {
    union { unsigned int i; float f; } v; v.i = u & 0xffff0000u; return v.f;
}
__device__ __forceinline__ float bf2f(short s) {
    union { unsigned int i; float f; } v; v.i = ((unsigned int)(unsigned short)s) << 16; return v.f;
}

// ---------------- K1: per-(chunk,slice) LDS histogram of one index array ------
__global__ __launch_bounds__(512) void csr_hist1(
    const int* __restrict__ idx, unsigned int* __restrict__ hist_g)
{
    __shared__ unsigned int hist[CHUNKW];   // 50 KB
    int c = blockIdx.x & (NCHUNK - 1), s = blockIdx.x >> 2;
    int t = threadIdx.x;
    for (int w = t; w < CHUNKW; w += 512) hist[w] = 0;
    __syncthreads();
    int base = s * SLICE_E;
    int lo = c * CHUNKN;
    for (int e = base + t; e < base + SLICE_E; e += 512) {
        unsigned int rl = (unsigned int)(idx[e] - lo);
        if (rl < CHUNKN) atomicAdd(&hist[rl >> 1], (rl & 1) ? 65536u : 1u);
    }
    __syncthreads();
    unsigned int* outp = hist_g + (size_t)blockIdx.x * CHUNKW;
    for (int w = t; w < CHUNKW; w += 512) outp[w] = hist[w];
}

// ------ K2: scan slice-partials -> offsets + padded cnt + real cnt + inv ------
__global__ __launch_bounds__(256) void csr_scan_blocks(
    const unsigned int* __restrict__ histR_g, const unsigned int* __restrict__ histS_g,
    unsigned short* __restrict__ blockoffR, int* __restrict__ cntPad,
    int* __restrict__ cntReal, float* __restrict__ inv_r, float* __restrict__ inv_s)
{
    int tid = blockIdx.x * blockDim.x + threadIdx.x;
    if (tid >= NCHUNK * CHUNKW) return;
    int c = tid / CHUNKW, w = tid - c * CHUNKW;
    int node = c * CHUNKN + 2 * w;
    unsigned int runLo = 0, runHi = 0;
#pragma unroll 8
    for (int s = 0; s < NSLICE; s++) {
        unsigned int v = histR_g[(size_t)(s * NCHUNK + c) * CHUNKW + w];
        *(unsigned int*)&blockoffR[(size_t)s * N_NODES + node] =
            (runLo & 0xffffu) | (runHi << 16);
        runLo += v & 0xffffu; runHi += v >> 16;
    }
    ((int2*)cntReal)[node >> 1] = make_int2((int)runLo, (int)runHi);
    ((int2*)cntPad)[node >> 1] =
        make_int2((int)((runLo + 7u) & ~7u), (int)((runHi + 7u) & ~7u));
    ((float2*)inv_r)[node >> 1] =
        make_float2(rsqrtf((float)(runLo + 1)), rsqrtf((float)(runHi + 1)));
    runLo = runHi = 0;
#pragma unroll 8
    for (int s = 0; s < NSLICE; s++) {
        unsigned int v = histS_g[(size_t)(s * NCHUNK + c) * CHUNKW + w];
        runLo += v & 0xffffu; runHi += v >> 16;
    }
    ((float2*)inv_s)[node >> 1] =
        make_float2(rsqrtf((float)(runLo + 1)), rsqrtf((float)(runHi + 1)));
}

// ---------------- exclusive scan of padded counts -> row_ptr ----------------
__global__ __launch_bounds__(256) void scan_blocksum(
    const int* __restrict__ cnt, int* __restrict__ partial)
{
    __shared__ int sred[256];
    int b = blockIdx.x, t = threadIdx.x;
    int base = b * 1024 + t * 4;
    int s = 0;
#pragma unroll
    for (int j = 0; j < 4; j++) {
        int i = base + j;
        s += (i < N_NODES) ? cnt[i] : 0;
    }
    sred[t] = s;
    __syncthreads();
    for (int off = 128; off > 0; off >>= 1) {
        if (t < off) sred[t] += sred[t + off];
        __syncthreads();
    }
    if (t == 0) partial[b] = sred[0];
}

__global__ __launch_bounds__(128) void scan_partials_par(int* partial, int nblk)
{
    __shared__ int lds[128];
    int t = threadIdx.x;
    int v = (t < nblk) ? partial[t] : 0;
    lds[t] = v;
    __syncthreads();
    for (int off = 1; off < 128; off <<= 1) {
        int add = (t >= off) ? lds[t - off] : 0;
        __syncthreads();
        lds[t] += add;
        __syncthreads();
    }
    if (t < nblk) partial[t] = lds[t] - v;   // exclusive
}

// scan_final also writes the pad slots of col (zero-row index N_NODES)
__global__ __launch_bounds__(256) void scan_final(
    const int* __restrict__ cnt, const int* __restrict__ cntReal,
    const int* __restrict__ partial, int* __restrict__ row_ptr,
    int* __restrict__ col)
{
    __shared__ int lds[256];
    int b = blockIdx.x, t = threadIdx.x;
    int base = b * 1024 + t * 4;
    int v[4]; int s = 0;
#pragma unroll
    for (int j = 0; j < 4; j++) {
        int i = base + j;
        v[j] = (i < N_NODES) ? cnt[i] : 0;
        s += v[j];
    }
    lds[t] = s;
    __syncthreads();
    for (int off = 1; off < 256; off <<= 1) {
        int add = (t >= off) ? lds[t - off] : 0;
        __syncthreads();
        lds[t] += add;
        __syncthreads();
    }
    int run = lds[t] - s + partial[b];
#pragma unroll
    for (int j = 0; j < 4; j++) {
        int i = base + j;
        if (i < N_NODES) {
            row_ptr[i] = run;
            int real = cntReal[i];
            for (int k = real; k < v[j]; k++) col[run + k] = N_NODES;
            run += v[j];
            if (i == N_NODES - 1) row_ptr[N_NODES] = run;
        }
    }
}

// ---------------- K3: scatter with LDS local ranks (no global atomics) --------
__global__ __launch_bounds__(512) void csr_scatter(
    const int* __restrict__ senders, const int* __restrict__ receivers,
    const int* __restrict__ row_ptr, const unsigned short* __restrict__ blockoffR,
    int* __restrict__ col)
{
    __shared__ unsigned int lrank[CHUNKW];   // 50 KB
    int c = blockIdx.x & (NCHUNK - 1), s = blockIdx.x >> 2;
    int t = threadIdx.x;
    for (int w = t; w < CHUNKW; w += 512) lrank[w] = 0;
    __syncthreads();
    int base = s * SLICE_E;
    int lo = c * CHUNKN;
    const unsigned short* boff = blockoffR + (size_t)s * N_NODES;
    for (int e = base + t; e < base + SLICE_E; e += 512) {
        int r  = receivers[e];
        int sd = senders[e];
        unsigned int rl = (unsigned int)(r - lo);
        if (rl < CHUNKN) {
            unsigned int old = atomicAdd(&lrank[rl >> 1], (rl & 1) ? 65536u : 1u);
            unsigned int lr = (rl & 1) ? (old >> 16) : (old & 0xffffu);
            col[row_ptr[r] + (int)boff[r] + (int)lr] = sd;
        }
    }
}

// ---------------- embed: xb = bf16(nodes @ W_embed + b_embed) + zero row ------
__global__ __launch_bounds__(256) void embed_kernel(
    const float* __restrict__ nodes, const float* __restrict__ We,
    const float* __restrict__ be, bf16* __restrict__ xb, bf16* __restrict__ h)
{
    int tid = blockIdx.x * blockDim.x + threadIdx.x;   // (node, col-chunk of 8)
    if (tid < 8) {   // zero row h[N_NODES] for padded-CSR gathers
        bf16x8 z = {};
        *(bf16x8*)&h[(size_t)N_NODES * 64 + tid * 8] = z;
    }
    if (tid >= N_NODES * 8) return;
    int i = tid >> 3, cc = tid & 7;
    float n0 = nodes[i * 3 + 0], n1 = nodes[i * 3 + 1], n2 = nodes[i * 3 + 2];
    union { bf16x8 v; bf16 h[8]; } pk;
#pragma unroll
    for (int k = 0; k < 8; k++) {
        int d = cc * 8 + k;
        float acc = be[d] + n0 * We[0 * 64 + d] + n1 * We[1 * 64 + d] + n2 * We[2 * 64 + d];
        pk.h[k] = __float2bfloat16(acc);
    }
    *(bf16x8*)&xb[(size_t)i * 64 + cc * 8] = pk.v;
}

// ---------------- W fragment pre-pack (f32 -> bf16, MFMA frag order) ----------
__global__ __launch_bounds__(256) void wfrag_kernel(
    const float* __restrict__ W0, const float* __restrict__ W1,
    bf16* __restrict__ frags)
{
    int tid = blockIdx.x * blockDim.x + threadIdx.x;
    if (tid >= 8192) return;
    int j    = tid & 7;
    int lane = (tid >> 3) & 63;
    int c    = (tid >> 9) & 1;
    int nt   = (tid >> 10) & 3;
    int L    = (tid >> 12) & 1;
    int g = lane >> 4, q = lane & 15;
    int k = c * 32 + g * 8 + j;
    int colIdx = nt * 16 + q;
    const float* W = L ? W1 : W0;
    frags[tid] = __float2bfloat16(W[k * 64 + colIdx]);
}

// ---------------- MFMA 2-layer MLP (+ inv_sqrt_s epilogue), bf16 ----------------
__global__ __launch_bounds__(256) void mlp_mfma(
    const bf16* __restrict__ xb, bf16* __restrict__ h,
    const bf16* __restrict__ wfrag,
    const float* __restrict__ b0, const float* __restrict__ b1,
    const float* __restrict__ inv_s)
{
    __shared__ char lds_raw[4][2048];
    int t = threadIdx.x;
    int w = t >> 6, lane = t & 63;
    int g = lane >> 4, q = lane & 15;
    char* myLds = lds_raw[w];

    bf16x8 wf[2][4][2];
#pragma unroll
    for (int L = 0; L < 2; L++)
#pragma unroll
        for (int nt = 0; nt < 4; nt++)
#pragma unroll
            for (int c = 0; c < 2; c++)
                wf[L][nt][c] = *(const bf16x8*)&wfrag[((((L * 4 + nt) * 2 + c) * 64) + lane) * 8];

    float bias0[4], bias1[4];
#pragma unroll
    for (int nt = 0; nt < 4; nt++) {
        bias0[nt] = b0[nt * 16 + q];
        bias1[nt] = b1[nt * 16 + q];
    }

    const int NTILES = N_NODES / 16;  // 6250
    for (int tile = blockIdx.x * 4 + w; tile < NTILES; tile += gridDim.x * 4) {
        int nodeBase = tile * 16;

        bf16x8 a0[2];
#pragma unroll
        for (int c = 0; c < 2; c++)
            a0[c] = *(const bf16x8*)&xb[(size_t)(nodeBase + q) * 64 + c * 32 + g * 8];

        f32x4 acc[4];
#pragma unroll
        for (int nt = 0; nt < 4; nt++) {
            acc[nt] = (f32x4){bias0[nt], bias0[nt], bias0[nt], bias0[nt]};
            acc[nt] = __builtin_amdgcn_mfma_f32_16x16x32_bf16(a0[0], wf[0][nt][0], acc[nt], 0, 0, 0);
            acc[nt] = __builtin_amdgcn_mfma_f32_16x16x32_bf16(a0[1], wf[0][nt][1], acc[nt], 0, 0, 0);
        }
#pragma unroll
        for (int nt = 0; nt < 4; nt++)
#pragma unroll
            for (int r = 0; r < 4; r++) {
                float v = fmaxf(acc[nt][r], 0.f);
                int node = g * 4 + r;
                int byte = ((node * 128 + (nt * 16 + q) * 2)) ^ ((node & 7) << 4);
                *(bf16*)(myLds + byte) = __float2bfloat16(v);
            }
        bf16x8 a1[2];
#pragma unroll
        for (int c = 0; c < 2; c++) {
            int byte = (q * 128 + c * 64 + g * 16) ^ ((q & 7) << 4);
            a1[c] = *(const bf16x8*)(myLds + byte);
        }

        f32x4 acc1[4];
#pragma unroll
        for (int nt = 0; nt < 4; nt++) {
            acc1[nt] = (f32x4){bias1[nt], bias1[nt], bias1[nt], bias1[nt]};
            acc1[nt] = __builtin_amdgcn_mfma_f32_16x16x32_bf16(a1[0], wf[1][nt][0], acc1[nt], 0, 0, 0);
            acc1[nt] = __builtin_amdgcn_mfma_f32_16x16x32_bf16(a1[1], wf[1][nt][1], acc1[nt], 0, 0, 0);
        }
        float is[4];
#pragma unroll
        for (int r = 0; r < 4; r++) is[r] = inv_s[nodeBase + g * 4 + r];
#pragma unroll
        for (int nt = 0; nt < 4; nt++)
#pragma unroll
            for (int r = 0; r < 4; r++) {
                float v = fmaxf(acc1[nt][r], 0.f) * is[r];
                int node = g * 4 + r;
                int byte = ((node * 128 + (nt * 16 + q) * 2)) ^ ((node & 7) << 4);
                *(bf16*)(myLds + byte) = __float2bfloat16(v);
            }
#pragma unroll
        for (int half = 0; half < 2; half++) {
            int byteL = lane * 32 + half * 16;
            int node = byteL >> 7;
            bf16x8 v = *(const bf16x8*)(myLds + (byteL ^ ((node & 7) << 4)));
            *(bf16x8*)&h[(size_t)nodeBase * 64 + lane * 16 + half * 8] = v;
        }
    }
}

// ------- gather-aggregate: padded rows, branch-free 8-edge loop + LN ----------
__global__ __launch_bounds__(256) void agg_ln_kernel(
    const bf16* __restrict__ h, bf16* __restrict__ xb,
    const int* __restrict__ row_ptr, const int* __restrict__ col,
    const float* __restrict__ inv_r,
    const float* __restrict__ ln_scale, const float* __restrict__ ln_bias)
{
    int t = threadIdx.x;
    int lane = t & 63;
    int sub = lane >> 5;          // which edge of the pair this half-wave handles
    int c = lane & 31;            // this lane covers columns 2c, 2c+1
    float2 lnsv = *(const float2*)&ln_scale[2 * c];
    float2 lnbv = *(const float2*)&ln_bias[2 * c];
    int gw = __builtin_amdgcn_readfirstlane((blockIdx.x * blockDim.x + t) >> 6);
    int nwaves = (gridDim.x * blockDim.x) >> 6;
    for (int i = gw; i < N_NODES; i += nwaves) {
        float a0 = 0.f, a1 = 0.f, b0 = 0.f, b1 = 0.f;
        // self edge (inv_s already folded into h); count once via sub==0
        unsigned int su = *(const unsigned int*)&h[(size_t)i * 64 + 2 * c];
        if (sub == 0) { a0 += blo(su); a1 += bhi(su); }
        int beg = row_ptr[i], end = row_ptr[i + 1];   // padded: (end-beg) % 8 == 0
        for (int e = beg; e < end; e += 8) {
            int r0 = col[e + 0 + sub];
            int r1 = col[e + 2 + sub];
            int r2 = col[e + 4 + sub];
            int r3 = col[e + 6 + sub];
            unsigned int u0 = *(const unsigned int*)&h[(size_t)r0 * 64 + 2 * c];
            unsigned int u1 = *(const unsigned int*)&h[(size_t)r1 * 64 + 2 * c];
            unsigned int u2 = *(const unsigned int*)&h[(size_t)r2 * 64 + 2 * c];
            unsigned int u3 = *(const unsigned int*)&h[(size_t)r3 * 64 + 2 * c];
            a0 += blo(u0) + blo(u1);
            a1 += bhi(u0) + bhi(u1);
            b0 += blo(u2) + blo(u3);
            b1 += bhi(u2) + bhi(u3);
        }
        a0 += b0; a1 += b1;
        // merge the two half-wave partial sums
        a0 += __shfl_xor(a0, 32);
        a1 += __shfl_xor(a1, 32);
        float ir = inv_r[i];
        unsigned int xu = *(const unsigned int*)&xb[(size_t)i * 64 + 2 * c];
        float y0 = a0 * ir + blo(xu);
        float y1 = a1 * ir + bhi(xu);
        // LayerNorm over 64 cols = 2 per lane x 32 lanes (duplicated across halves)
        float sum = y0 + y1;
#pragma unroll
        for (int m = 1; m < 32; m <<= 1) sum += __shfl_xor(sum, m);
        float mu = sum * (1.f / 64.f);
        float d0 = y0 - mu, d1 = y1 - mu;
        float vs = d0 * d0 + d1 * d1;
#pragma unroll
        for (int m = 1; m < 32; m <<= 1) vs += __shfl_xor(vs, m);
        float var = vs * (1.f / 64.f);
        float rr = rsqrtf(var + 1e-6f);
        float o0 = d0 * rr * lnsv.x + lnbv.x;
        float o1 = d1 * rr * lnsv.y + lnbv.y;
        if (sub == 0) {
            union { unsigned int u; bf16 h2[2]; } pk;
            pk.h2[0] = __float2bfloat16(o0);
            pk.h2[1] = __float2bfloat16(o1);
            *(unsigned int*)&xb[(size_t)i * 64 + 2 * c] = pk.u;
        }
    }
}

// ---------------- pool stage 1: partial sums, vectorized bf16x8 loads ---------
__global__ __launch_bounds__(256) void pool_stage1(
    const bf16* __restrict__ xb, const int* __restrict__ n_node,
    float* __restrict__ partialP)   // [N_GRAPH][POOL_PB][64]
{
    __shared__ float red[32][8][8];  // 8 KB
    int b = blockIdx.x;
    int g = b >> 3, sub = b & 7;
    int t = threadIdx.x;
    int start = 0;
    for (int j = 0; j < g; j++) start += n_node[j];
    int cnt = n_node[g];
    int jbeg = (int)(((long long)cnt * sub) / POOL_PB);
    int jend = (int)(((long long)cnt * (sub + 1)) / POOL_PB);
    int rg = t >> 3, cc = t & 7;
    float acc[8];
#pragma unroll
    for (int k = 0; k < 8; k++) acc[k] = 0.f;
    for (int j = jbeg + rg; j < jend; j += 32) {
        bf16x8 v = *(const bf16x8*)&xb[(size_t)(start + j) * 64 + cc * 8];
#pragma unroll
        for (int k = 0; k < 8; k++) acc[k] += bf2f(v[k]);
    }
#pragma unroll
    for (int k = 0; k < 8; k++) red[rg][cc][k] = acc[k];
    __syncthreads();
    if (t < 64) {
        float s = 0.f;
#pragma unroll 8
        for (int r = 0; r < 32; r++) s += red[r][t >> 3][t & 7];
        partialP[((size_t)g * POOL_PB + sub) * 64 + t] = s;
    }
}

// ---------------- pool stage 2: reduce partials + mean + decoder GEMV ---------
__global__ __launch_bounds__(64) void pool_stage2(
    const float* __restrict__ partialP, const int* __restrict__ n_node,
    const float* __restrict__ Wg, const float* __restrict__ bg,
    float* __restrict__ out)
{
    __shared__ float pd[64];
    int g = blockIdx.x;
    int t = threadIdx.x;
    float s = 0.f;
#pragma unroll
    for (int p = 0; p < POOL_PB; p++) s += partialP[((size_t)g * POOL_PB + p) * 64 + t];
    int cnt = n_node[g];
    pd[t] = s / fmaxf((float)cnt, 1.f);
    __syncthreads();
    if (t < OUT_G) {
        float v = bg[t];
#pragma unroll 16
        for (int dd = 0; dd < 64; dd++) v += pd[dd] * Wg[dd * OUT_G + t];
        out[g * OUT_G + t] = v;
    }
}

extern "C" void kernel_launch(void* const* d_in, const int* in_sizes, int n_in,
                              void* d_out, int out_size, void* d_ws, size_t ws_size,
                              hipStream_t stream) {
    const float* nodes    = (const float*)d_in[0];
    const int*   senders  = (const int*)d_in[1];
    const int*   receivers= (const int*)d_in[2];
    const int*   n_node   = (const int*)d_in[3];
    const float* W_embed  = (const float*)d_in[4];
    const float* b_embed  = (const float*)d_in[5];
    const float* W_mlp0   = (const float*)d_in[6];
    const float* b_mlp0   = (const float*)d_in[7];
    const float* W_mlp1   = (const float*)d_in[8];
    const float* b_mlp1   = (const float*)d_in[9];
    const float* ln_scale = (const float*)d_in[10];
    const float* ln_bias  = (const float*)d_in[11];
    const float* W_glob   = (const float*)d_in[12];
    const float* b_glob   = (const float*)d_in[13];
    float* out = (float*)d_out;

    // workspace layout (16B-aligned pieces)
    char* ws = (char*)d_ws;
    bf16*  xb     = (bf16*)ws;    ws += (size_t)N_NODES * 64 * 2;        // 12.8 MB
    bf16*  h      = (bf16*)ws;    ws += (size_t)(N_NODES + 1) * 64 * 2;  // 12.8 MB + zero row
    unsigned int* histS_g = (unsigned int*)ws; ws += (size_t)NSLICE * NCHUNK * CHUNKW * 4; // 12.8 MB
    float* inv_s  = (float*)ws;   ws += (size_t)N_NODES * 4;
    float* inv_r  = (float*)ws;   ws += (size_t)N_NODES * 4;
    int*   cntPad = (int*)ws;     ws += (size_t)N_NODES * 4;
    int*   cntReal= (int*)ws;     ws += (size_t)N_NODES * 4;
    int*   row_ptr= (int*)ws;     ws += (size_t)(N_NODES + 4) * 4;
    int*   col    = (int*)ws;     ws += (size_t)COL_CAP * 4;             // 9.2 MB
    int*   partial= (int*)ws;     ws += 256 * 4;
    bf16*  wfrag  = (bf16*)ws;    ws += 8192 * 2;
    float* partialP = (float*)ws; ws += (size_t)N_GRAPH * POOL_PB * 64 * 4;

    // CSR-build temporaries alias h/xb (dead until the step loop)
    unsigned int*   histR_g   = (unsigned int*)h;     // read before mlp writes h
    unsigned short* blockoffR = (unsigned short*)xb;  // read before embed writes xb

    const int nblk_scan = (N_NODES + 1023) / 1024;  // 98

    // ---- CSR build (no global atomics), padded rows ----
    csr_hist1<<<NSLICE * NCHUNK, 512, 0, stream>>>(receivers, histR_g);
    csr_hist1<<<NSLICE * NCHUNK, 512, 0, stream>>>(senders, histS_g);
    csr_scan_blocks<<<(NCHUNK * CHUNKW + 255) / 256, 256, 0, stream>>>(
        histR_g, histS_g, blockoffR, cntPad, cntReal, inv_r, inv_s);
    scan_blocksum<<<nblk_scan, 256, 0, stream>>>(cntPad, partial);
    scan_partials_par<<<1, 128, 0, stream>>>(partial, nblk_scan);
    scan_final<<<nblk_scan, 256, 0, stream>>>(cntPad, cntReal, partial, row_ptr, col);
    csr_scatter<<<NSLICE * NCHUNK, 512, 0, stream>>>(senders, receivers, row_ptr, blockoffR, col);

    // ---- embed (after CSR temporaries are dead) ----
    embed_kernel<<<(N_NODES * 8 + 255) / 256, 256, 0, stream>>>(nodes, W_embed, b_embed, xb, h);
    wfrag_kernel<<<32, 256, 0, stream>>>(W_mlp0, W_mlp1, wfrag);

    for (int step = 0; step < N_STEPS; ++step) {
        mlp_mfma<<<1563, 256, 0, stream>>>(xb, h, wfrag, b_mlp0, b_mlp1, inv_s);
        agg_ln_kernel<<<4096, 256, 0, stream>>>(h, xb, row_ptr, col, inv_r, ln_scale, ln_bias);
    }

    pool_stage1<<<N_GRAPH * POOL_PB, 256, 0, stream>>>(xb, n_node, partialP);
    pool_stage2<<<N_GRAPH, 64, 0, stream>>>(partialP, n_node, W_glob, b_glob, out);
}

// Round 11
// 352.313 us; speedup vs baseline: 1.2056x; 1.0645x over previous
//
#include <hip/hip_runtime.h>
#include <hip/hip_bf16.h>

#define N_NODES 100000
#define N_EDGES 1600000
#define LATENT 64
#define N_GRAPH 100
#define OUT_G 16
#define N_STEPS 3

// CSR-build geometry
#define NCHUNK 4
#define CHUNKN 25000            // nodes per chunk
#define CHUNKW 12500            // packed u16-pair words per chunk (50 KB LDS)
#define NSLICE 64
#define SLICE_E 25000           // edges per slice

#define POOL_PB 8               // stage-1 blocks per graph
#define COL_CAP (N_EDGES + 7 * N_NODES + 64)   // padded CSR capacity

using bf16 = __hip_bfloat16;
using bf16x8 = __attribute__((ext_vector_type(8))) short;
using f32x4  = __attribute__((ext_vector_type(4))) float;

__device__ __forceinline__ float blo(unsigned int u) {
    union { unsigned int i; float f; } v; v.i = u << 16; return v.f;
}
__device__ __forceinline__ float bhi(unsigned int u) {
    union { unsigned int i; float f; } v; v.i = u & 0xffff0000u; return v.f;
}
__device__ __forceinline__ float bf2f(short s) {
    union { unsigned int i; float f; } v; v.i = ((unsigned int)(unsigned short)s) << 16; return v.f;
}

// ------- K1: per-(chunk,slice) LDS histogram; R-half and S-half in one grid ----
__global__ __launch_bounds__(512) void csr_hist_both(
    const int* __restrict__ receivers, const int* __restrict__ senders,
    unsigned int* __restrict__ histR_g, unsigned int* __restrict__ histS_g)
{
    __shared__ unsigned int hist[CHUNKW];   // 50 KB
    int b = blockIdx.x;
    int isS = (b >= NSLICE * NCHUNK);
    int bb = b - isS * NSLICE * NCHUNK;
    const int* idx = isS ? senders : receivers;
    unsigned int* outg = (isS ? histS_g : histR_g) + (size_t)bb * CHUNKW;
    int c = bb & (NCHUNK - 1), s = bb >> 2;
    int t = threadIdx.x;
    for (int w = t; w < CHUNKW; w += 512) hist[w] = 0;
    __syncthreads();
    int base = s * SLICE_E;
    int lo = c * CHUNKN;
    for (int e = base + t; e < base + SLICE_E; e += 512) {
        unsigned int rl = (unsigned int)(idx[e] - lo);
        if (rl < CHUNKN) atomicAdd(&hist[rl >> 1], (rl & 1) ? 65536u : 1u);
    }
    __syncthreads();
    for (int w = t; w < CHUNKW; w += 512) outg[w] = hist[w];
}

// ------ K2: scan slice-partials -> offsets + padded cnt + real cnt + inv ------
__global__ __launch_bounds__(256) void csr_scan_blocks(
    const unsigned int* __restrict__ histR_g, const unsigned int* __restrict__ histS_g,
    unsigned short* __restrict__ blockoffR, int* __restrict__ cntPad,
    int* __restrict__ cntReal, float* __restrict__ inv_r, float* __restrict__ inv_s)
{
    int tid = blockIdx.x * blockDim.x + threadIdx.x;
    if (tid >= NCHUNK * CHUNKW) return;
    int c = tid / CHUNKW, w = tid - c * CHUNKW;
    int node = c * CHUNKN + 2 * w;
    unsigned int runLo = 0, runHi = 0;
#pragma unroll 8
    for (int s = 0; s < NSLICE; s++) {
        unsigned int v = histR_g[(size_t)(s * NCHUNK + c) * CHUNKW + w];
        *(unsigned int*)&blockoffR[(size_t)s * N_NODES + node] =
            (runLo & 0xffffu) | (runHi << 16);
        runLo += v & 0xffffu; runHi += v >> 16;
    }
    ((int2*)cntReal)[node >> 1] = make_int2((int)runLo, (int)runHi);
    ((int2*)cntPad)[node >> 1] =
        make_int2((int)((runLo + 7u) & ~7u), (int)((runHi + 7u) & ~7u));
    ((float2*)inv_r)[node >> 1] =
        make_float2(rsqrtf((float)(runLo + 1)), rsqrtf((float)(runHi + 1)));
    runLo = runHi = 0;
#pragma unroll 8
    for (int s = 0; s < NSLICE; s++) {
        unsigned int v = histS_g[(size_t)(s * NCHUNK + c) * CHUNKW + w];
        runLo += v & 0xffffu; runHi += v >> 16;
    }
    ((float2*)inv_s)[node >> 1] =
        make_float2(rsqrtf((float)(runLo + 1)), rsqrtf((float)(runHi + 1)));
}

// ---------------- exclusive scan of padded counts -> row_ptr ----------------
__global__ __launch_bounds__(256) void scan_blocksum(
    const int* __restrict__ cnt, int* __restrict__ partial)
{
    __shared__ int sred[256];
    int b = blockIdx.x, t = threadIdx.x;
    int base = b * 1024 + t * 4;
    int s = 0;
#pragma unroll
    for (int j = 0; j < 4; j++) {
        int i = base + j;
        s += (i < N_NODES) ? cnt[i] : 0;
    }
    sred[t] = s;
    __syncthreads();
    for (int off = 128; off > 0; off >>= 1) {
        if (t < off) sred[t] += sred[t + off];
        __syncthreads();
    }
    if (t == 0) partial[b] = sred[0];
}

__global__ __launch_bounds__(128) void scan_partials_par(int* partial, int nblk)
{
    __shared__ int lds[128];
    int t = threadIdx.x;
    int v = (t < nblk) ? partial[t] : 0;
    lds[t] = v;
    __syncthreads();
    for (int off = 1; off < 128; off <<= 1) {
        int add = (t >= off) ? lds[t - off] : 0;
        __syncthreads();
        lds[t] += add;
        __syncthreads();
    }
    if (t < nblk) partial[t] = lds[t] - v;   // exclusive
}

// scan_final also writes the pad slots of col (zero-row index N_NODES)
__global__ __launch_bounds__(256) void scan_final(
    const int* __restrict__ cnt, const int* __restrict__ cntReal,
    const int* __restrict__ partial, int* __restrict__ row_ptr,
    int* __restrict__ col)
{
    __shared__ int lds[256];
    int b = blockIdx.x, t = threadIdx.x;
    int base = b * 1024 + t * 4;
    int v[4]; int s = 0;
#pragma unroll
    for (int j = 0; j < 4; j++) {
        int i = base + j;
        v[j] = (i < N_NODES) ? cnt[i] : 0;
        s += v[j];
    }
    lds[t] = s;
    __syncthreads();
    for (int off = 1; off < 256; off <<= 1) {
        int add = (t >= off) ? lds[t - off] : 0;
        __syncthreads();
        lds[t] += add;
        __syncthreads();
    }
    int run = lds[t] - s + partial[b];
#pragma unroll
    for (int j = 0; j < 4; j++) {
        int i = base + j;
        if (i < N_NODES) {
            row_ptr[i] = run;
            int real = cntReal[i];
            for (int k = real; k < v[j]; k++) col[run + k] = N_NODES;
            run += v[j];
            if (i == N_NODES - 1) row_ptr[N_NODES] = run;
        }
    }
}

// ---------------- K3: scatter with LDS local ranks (no global atomics) --------
__global__ __launch_bounds__(512) void csr_scatter(
    const int* __restrict__ senders, const int* __restrict__ receivers,
    const int* __restrict__ row_ptr, const unsigned short* __restrict__ blockoffR,
    int* __restrict__ col)
{
    __shared__ unsigned int lrank[CHUNKW];   // 50 KB
    int c = blockIdx.x & (NCHUNK - 1), s = blockIdx.x >> 2;
    int t = threadIdx.x;
    for (int w = t; w < CHUNKW; w += 512) lrank[w] = 0;
    __syncthreads();
    int base = s * SLICE_E;
    int lo = c * CHUNKN;
    const unsigned short* boff = blockoffR + (size_t)s * N_NODES;
    for (int e = base + t; e < base + SLICE_E; e += 512) {
        int r  = receivers[e];
        int sd = senders[e];
        unsigned int rl = (unsigned int)(r - lo);
        if (rl < CHUNKN) {
            unsigned int old = atomicAdd(&lrank[rl >> 1], (rl & 1) ? 65536u : 1u);
            unsigned int lr = (rl & 1) ? (old >> 16) : (old & 0xffffu);
            col[row_ptr[r] + (int)boff[r] + (int)lr] = sd;
        }
    }
}

// ---------------- embed: xb = bf16(nodes @ W_embed + b_embed) + zero row ------
__global__ __launch_bounds__(256) void embed_kernel(
    const float* __restrict__ nodes, const float* __restrict__ We,
    const float* __restrict__ be, bf16* __restrict__ xb, bf16* __restrict__ h)
{
    int tid = blockIdx.x * blockDim.x + threadIdx.x;   // (node, col-chunk of 8)
    if (tid < 8) {   // zero row h[N_NODES] for padded-CSR gathers
        bf16x8 z = {};
        *(bf16x8*)&h[(size_t)N_NODES * 64 + tid * 8] = z;
    }
    if (tid >= N_NODES * 8) return;
    int i = tid >> 3, cc = tid & 7;
    float n0 = nodes[i * 3 + 0], n1 = nodes[i * 3 + 1], n2 = nodes[i * 3 + 2];
    union { bf16x8 v; bf16 h[8]; } pk;
#pragma unroll
    for (int k = 0; k < 8; k++) {
        int d = cc * 8 + k;
        float acc = be[d] + n0 * We[0 * 64 + d] + n1 * We[1 * 64 + d] + n2 * We[2 * 64 + d];
        pk.h[k] = __float2bfloat16(acc);
    }
    *(bf16x8*)&xb[(size_t)i * 64 + cc * 8] = pk.v;
}

// ---------------- W fragment pre-pack (f32 -> bf16, MFMA frag order) ----------
__global__ __launch_bounds__(256) void wfrag_kernel(
    const float* __restrict__ W0, const float* __restrict__ W1,
    bf16* __restrict__ frags)
{
    int tid = blockIdx.x * blockDim.x + threadIdx.x;
    if (tid >= 8192) return;
    int j    = tid & 7;
    int lane = (tid >> 3) & 63;
    int c    = (tid >> 9) & 1;
    int nt   = (tid >> 10) & 3;
    int L    = (tid >> 12) & 1;
    int g = lane >> 4, q = lane & 15;
    int k = c * 32 + g * 8 + j;
    int colIdx = nt * 16 + q;
    const float* W = L ? W1 : W0;
    frags[tid] = __float2bfloat16(W[k * 64 + colIdx]);
}

// ---------------- MFMA 2-layer MLP (+ inv_sqrt_s epilogue), bf16 ----------------
__global__ __launch_bounds__(256) void mlp_mfma(
    const bf16* __restrict__ xb, bf16* __restrict__ h,
    const bf16* __restrict__ wfrag,
    const float* __restrict__ b0, const float* __restrict__ b1,
    const float* __restrict__ inv_s)
{
    __shared__ char lds_raw[4][2048];
    int t = threadIdx.x;
    int w = t >> 6, lane = t & 63;
    int g = lane >> 4, q = lane & 15;
    char* myLds = lds_raw[w];

    bf16x8 wf[2][4][2];
#pragma unroll
    for (int L = 0; L < 2; L++)
#pragma unroll
        for (int nt = 0; nt < 4; nt++)
#pragma unroll
            for (int c = 0; c < 2; c++)
                wf[L][nt][c] = *(const bf16x8*)&wfrag[((((L * 4 + nt) * 2 + c) * 64) + lane) * 8];

    float bias0[4], bias1[4];
#pragma unroll
    for (int nt = 0; nt < 4; nt++) {
        bias0[nt] = b0[nt * 16 + q];
        bias1[nt] = b1[nt * 16 + q];
    }

    const int NTILES = N_NODES / 16;  // 6250
    for (int tile = blockIdx.x * 4 + w; tile < NTILES; tile += gridDim.x * 4) {
        int nodeBase = tile * 16;

        bf16x8 a0[2];
#pragma unroll
        for (int c = 0; c < 2; c++)
            a0[c] = *(const bf16x8*)&xb[(size_t)(nodeBase + q) * 64 + c * 32 + g * 8];

        f32x4 acc[4];
#pragma unroll
        for (int nt = 0; nt < 4; nt++) {
            acc[nt] = (f32x4){bias0[nt], bias0[nt], bias0[nt], bias0[nt]};
            acc[nt] = __builtin_amdgcn_mfma_f32_16x16x32_bf16(a0[0], wf[0][nt][0], acc[nt], 0, 0, 0);
            acc[nt] = __builtin_amdgcn_mfma_f32_16x16x32_bf16(a0[1], wf[0][nt][1], acc[nt], 0, 0, 0);
        }
#pragma unroll
        for (int nt = 0; nt < 4; nt++)
#pragma unroll
            for (int r = 0; r < 4; r++) {
                float v = fmaxf(acc[nt][r], 0.f);
                int node = g * 4 + r;
                int byte = ((node * 128 + (nt * 16 + q) * 2)) ^ ((node & 7) << 4);
                *(bf16*)(myLds + byte) = __float2bfloat16(v);
            }
        bf16x8 a1[2];
#pragma unroll
        for (int c = 0; c < 2; c++) {
            int byte = (q * 128 + c * 64 + g * 16) ^ ((q & 7) << 4);
            a1[c] = *(const bf16x8*)(myLds + byte);
        }

        f32x4 acc1[4];
#pragma unroll
        for (int nt = 0; nt < 4; nt++) {
            acc1[nt] = (f32x4){bias1[nt], bias1[nt], bias1[nt], bias1[nt]};
            acc1[nt] = __builtin_amdgcn_mfma_f32_16x16x32_bf16(a1[0], wf[1][nt][0], acc1[nt], 0, 0, 0);
            acc1[nt] = __builtin_amdgcn_mfma_f32_16x16x32_bf16(a1[1], wf[1][nt][1], acc1[nt], 0, 0, 0);
        }
        float is[4];
#pragma unroll
        for (int r = 0; r < 4; r++) is[r] = inv_s[nodeBase + g * 4 + r];
#pragma unroll
        for (int nt = 0; nt < 4; nt++)
#pragma unroll
            for (int r = 0; r < 4; r++) {
                float v = fmaxf(acc1[nt][r], 0.f) * is[r];
                int node = g * 4 + r;
                int byte = ((node * 128 + (nt * 16 + q) * 2)) ^ ((node & 7) << 4);
                *(bf16*)(myLds + byte) = __float2bfloat16(v);
            }
#pragma unroll
        for (int half = 0; half < 2; half++) {
            int byteL = lane * 32 + half * 16;
            int node = byteL >> 7;
            bf16x8 v = *(const bf16x8*)(myLds + (byteL ^ ((node & 7) << 4)));
            *(bf16x8*)&h[(size_t)nodeBase * 64 + lane * 16 + half * 8] = v;
        }
    }
}

// --- gather-aggregate: 4-slot lanes, uint2 gathers, prefetched col, LN --------
__global__ __launch_bounds__(256) void agg_ln_kernel(
    const bf16* __restrict__ h, bf16* __restrict__ xb,
    const int* __restrict__ row_ptr, const int* __restrict__ col,
    const float* __restrict__ inv_r,
    const float* __restrict__ ln_scale, const float* __restrict__ ln_bias)
{
    int t = threadIdx.x;
    int lane = t & 63;
    int sub = lane >> 4;          // edge-slot 0..3
    int q = lane & 15;            // this lane covers columns 4q..4q+3
    float4 lnsv = *(const float4*)&ln_scale[4 * q];
    float4 lnbv = *(const float4*)&ln_bias[4 * q];
    int gw = __builtin_amdgcn_readfirstlane((blockIdx.x * blockDim.x + t) >> 6);
    int nwaves = (gridDim.x * blockDim.x) >> 6;
    for (int i = gw; i < N_NODES; i += nwaves) {
        float a0 = 0.f, a1 = 0.f, a2 = 0.f, a3 = 0.f;
        // self edge (inv_s already folded into h); count once via sub==0
        uint2 su = *(const uint2*)&h[(size_t)i * 64 + 4 * q];
        if (sub == 0) {
            a0 = blo(su.x); a1 = bhi(su.x); a2 = blo(su.y); a3 = bhi(su.y);
        }
        int beg = row_ptr[i], end = row_ptr[i + 1];   // padded: (end-beg) % 8 == 0
        int2 ci = *(const int2*)&col[beg + 2 * sub];
        for (int e = beg; e < end; e += 8) {
            int ne = e + 8;
            int2 cn = (ne < end) ? *(const int2*)&col[ne + 2 * sub]
                                 : make_int2(N_NODES, N_NODES);
            uint2 u0 = *(const uint2*)&h[(size_t)ci.x * 64 + 4 * q];
            uint2 u1 = *(const uint2*)&h[(size_t)ci.y * 64 + 4 * q];
            a0 += blo(u0.x) + blo(u1.x);
            a1 += bhi(u0.x) + bhi(u1.x);
            a2 += blo(u0.y) + blo(u1.y);
            a3 += bhi(u0.y) + bhi(u1.y);
            ci = cn;
        }
        // merge the 4 edge-slot partials (bits 4,5 of lane)
        a0 += __shfl_xor(a0, 16); a0 += __shfl_xor(a0, 32);
        a1 += __shfl_xor(a1, 16); a1 += __shfl_xor(a1, 32);
        a2 += __shfl_xor(a2, 16); a2 += __shfl_xor(a2, 32);
        a3 += __shfl_xor(a3, 16); a3 += __shfl_xor(a3, 32);
        float ir = inv_r[i];
        uint2 xu = *(const uint2*)&xb[(size_t)i * 64 + 4 * q];
        float y0 = a0 * ir + blo(xu.x);
        float y1 = a1 * ir + bhi(xu.x);
        float y2 = a2 * ir + blo(xu.y);
        float y3 = a3 * ir + bhi(xu.y);
        // LayerNorm over 64 cols = 4 per lane x 16 lanes (duplicated across subs)
        float sum = (y0 + y1) + (y2 + y3);
#pragma unroll
        for (int m = 1; m < 16; m <<= 1) sum += __shfl_xor(sum, m);
        float mu = sum * (1.f / 64.f);
        float d0 = y0 - mu, d1 = y1 - mu, d2 = y2 - mu, d3 = y3 - mu;
        float vs = (d0 * d0 + d1 * d1) + (d2 * d2 + d3 * d3);
#pragma unroll
        for (int m = 1; m < 16; m <<= 1) vs += __shfl_xor(vs, m);
        float var = vs * (1.f / 64.f);
        float rr = rsqrtf(var + 1e-6f);
        float o0 = d0 * rr * lnsv.x + lnbv.x;
        float o1 = d1 * rr * lnsv.y + lnbv.y;
        float o2 = d2 * rr * lnsv.z + lnbv.z;
        float o3 = d3 * rr * lnsv.w + lnbv.w;
        if (sub == 0) {
            union { uint2 u; bf16 h4[4]; } pk;
            pk.h4[0] = __float2bfloat16(o0);
            pk.h4[1] = __float2bfloat16(o1);
            pk.h4[2] = __float2bfloat16(o2);
            pk.h4[3] = __float2bfloat16(o3);
            *(uint2*)&xb[(size_t)i * 64 + 4 * q] = pk.u;
        }
    }
}

// ---------------- pool stage 1: partial sums, vectorized bf16x8 loads ---------
__global__ __launch_bounds__(256) void pool_stage1(
    const bf16* __restrict__ xb, const int* __restrict__ n_node,
    float* __restrict__ partialP)   // [N_GRAPH][POOL_PB][64]
{
    __shared__ float red[32][8][8];  // 8 KB
    int b = blockIdx.x;
    int g = b >> 3, sub = b & 7;
    int t = threadIdx.x;
    int start = 0;
    for (int j = 0; j < g; j++) start += n_node[j];
    int cnt = n_node[g];
    int jbeg = (int)(((long long)cnt * sub) / POOL_PB);
    int jend = (int)(((long long)cnt * (sub + 1)) / POOL_PB);
    int rg = t >> 3, cc = t & 7;
    float acc[8];
#pragma unroll
    for (int k = 0; k < 8; k++) acc[k] = 0.f;
    for (int j = jbeg + rg; j < jend; j += 32) {
        bf16x8 v = *(const bf16x8*)&xb[(size_t)(start + j) * 64 + cc * 8];
#pragma unroll
        for (int k = 0; k < 8; k++) acc[k] += bf2f(v[k]);
    }
#pragma unroll
    for (int k = 0; k < 8; k++) red[rg][cc][k] = acc[k];
    __syncthreads();
    if (t < 64) {
        float s = 0.f;
#pragma unroll 8
        for (int r = 0; r < 32; r++) s += red[r][t >> 3][t & 7];
        partialP[((size_t)g * POOL_PB + sub) * 64 + t] = s;
    }
}

// ---------------- pool stage 2: reduce partials + mean + decoder GEMV ---------
__global__ __launch_bounds__(64) void pool_stage2(
    const float* __restrict__ partialP, const int* __restrict__ n_node,
    const float* __restrict__ Wg, const float* __restrict__ bg,
    float* __restrict__ out)
{
    __shared__ float pd[64];
    int g = blockIdx.x;
    int t = threadIdx.x;
    float s = 0.f;
#pragma unroll
    for (int p = 0; p < POOL_PB; p++) s += partialP[((size_t)g * POOL_PB + p) * 64 + t];
    int cnt = n_node[g];
    pd[t] = s / fmaxf((float)cnt, 1.f);
    __syncthreads();
    if (t < OUT_G) {
        float v = bg[t];
#pragma unroll 16
        for (int dd = 0; dd < 64; dd++) v += pd[dd] * Wg[dd * OUT_G + t];
        out[g * OUT_G + t] = v;
    }
}

extern "C" void kernel_launch(void* const* d_in, const int* in_sizes, int n_in,
                              void* d_out, int out_size, void* d_ws, size_t ws_size,
                              hipStream_t stream) {
    const float* nodes    = (const float*)d_in[0];
    const int*   senders  = (const int*)d_in[1];
    const int*   receivers= (const int*)d_in[2];
    const int*   n_node   = (const int*)d_in[3];
    const float* W_embed  = (const float*)d_in[4];
    const float* b_embed  = (const float*)d_in[5];
    const float* W_mlp0   = (const float*)d_in[6];
    const float* b_mlp0   = (const float*)d_in[7];
    const float* W_mlp1   = (const float*)d_in[8];
    const float* b_mlp1   = (const float*)d_in[9];
    const float* ln_scale = (const float*)d_in[10];
    const float* ln_bias  = (const float*)d_in[11];
    const float* W_glob   = (const float*)d_in[12];
    const float* b_glob   = (const float*)d_in[13];
    float* out = (float*)d_out;

    // workspace layout (16B-aligned pieces)
    char* ws = (char*)d_ws;
    bf16*  xb     = (bf16*)ws;    ws += (size_t)N_NODES * 64 * 2;        // 12.8 MB
    bf16*  h      = (bf16*)ws;    ws += (size_t)(N_NODES + 1) * 64 * 2;  // 12.8 MB + zero row
    unsigned int* histS_g = (unsigned int*)ws; ws += (size_t)NSLICE * NCHUNK * CHUNKW * 4; // 12.8 MB
    float* inv_s  = (float*)ws;   ws += (size_t)N_NODES * 4;
    float* inv_r  = (float*)ws;   ws += (size_t)N_NODES * 4;
    int*   cntPad = (int*)ws;     ws += (size_t)N_NODES * 4;
    int*   cntReal= (int*)ws;     ws += (size_t)N_NODES * 4;
    int*   row_ptr= (int*)ws;     ws += (size_t)(N_NODES + 4) * 4;
    int*   col    = (int*)ws;     ws += (size_t)COL_CAP * 4;             // 9.2 MB
    int*   partial= (int*)ws;     ws += 256 * 4;
    bf16*  wfrag  = (bf16*)ws;    ws += 8192 * 2;
    float* partialP = (float*)ws; ws += (size_t)N_GRAPH * POOL_PB * 64 * 4;

    // CSR-build temporaries alias h/xb (dead until the step loop)
    unsigned int*   histR_g   = (unsigned int*)h;     // read before mlp writes h
    unsigned short* blockoffR = (unsigned short*)xb;  // read before embed writes xb

    const int nblk_scan = (N_NODES + 1023) / 1024;  // 98

    // ---- CSR build (no global atomics), padded rows ----
    csr_hist_both<<<2 * NSLICE * NCHUNK, 512, 0, stream>>>(receivers, senders, histR_g, histS_g);
    csr_scan_blocks<<<(NCHUNK * CHUNKW + 255) / 256, 256, 0, stream>>>(
        histR_g, histS_g, blockoffR, cntPad, cntReal, inv_r, inv_s);
    scan_blocksum<<<nblk_scan, 256, 0, stream>>>(cntPad, partial);
    scan_partials_par<<<1, 128, 0, stream>>>(partial, nblk_scan);
    scan_final<<<nblk_scan, 256, 0, stream>>>(cntPad, cntReal, partial, row_ptr, col);
    csr_scatter<<<NSLICE * NCHUNK, 512, 0, stream>>>(senders, receivers, row_ptr, blockoffR, col);

    // ---- embed (after CSR temporaries are dead) ----
    embed_kernel<<<(N_NODES * 8 + 255) / 256, 256, 0, stream>>>(nodes, W_embed, b_embed, xb, h);
    wfrag_kernel<<<32, 256, 0, stream>>>(W_mlp0, W_mlp1, wfrag);

    for (int step = 0; step < N_STEPS; ++step) {
        mlp_mfma<<<1563, 256, 0, stream>>>(xb, h, wfrag, b_mlp0, b_mlp1, inv_s);
        agg_ln_kernel<<<4096, 256, 0, stream>>>(h, xb, row_ptr, col, inv_r, ln_scale, ln_bias);
    }

    pool_stage1<<<N_GRAPH * POOL_PB, 256, 0, stream>>>(xb, n_node, partialP);
    pool_stage2<<<N_GRAPH, 64, 0, stream>>>(partialP, n_node, W_glob, b_glob, out);
}

// Round 12
// 347.727 us; speedup vs baseline: 1.2215x; 1.0132x over previous
//
#include <hip/hip_runtime.h>
#include <hip/hip_bf16.h>
#include <hip/hip_fp8.h>

#define N_NODES 100000
#define N_EDGES 1600000
#define LATENT 64
#define N_GRAPH 100
#define OUT_G 16
#define N_STEPS 3

// CSR-build geometry
#define NCHUNK 4
#define CHUNKN 25000            // nodes per chunk
#define CHUNKW 12500            // packed u16-pair words per chunk (50 KB LDS)
#define NSLICE 64
#define SLICE_E 25000           // edges per slice

#define POOL_PB 8               // stage-1 blocks per graph
#define COL_CAP (N_EDGES + 7 * N_NODES + 64)   // padded CSR capacity

using bf16 = __hip_bfloat16;
using bf16x8 = __attribute__((ext_vector_type(8))) short;
using f32x4  = __attribute__((ext_vector_type(4))) float;

__device__ __forceinline__ float blo(unsigned int u) {
    union { unsigned int i; float f; } v; v.i = u << 16; return v.f;
}
__device__ __forceinline__ float bhi(unsigned int u) {
    union { unsigned int i; float f; } v; v.i = u & 0xffff0000u; return v.f;
}
__device__ __forceinline__ float bf2f(short s) {
    union { unsigned int i; float f; } v; v.i = ((unsigned int)(unsigned short)s) << 16; return v.f;
}
// 4 packed fp8 e4m3 -> 4 floats (native cvt on gfx950)
__device__ __forceinline__ float4 fp8x4(unsigned int u) {
    union { unsigned int w; __hip_fp8_storage_t b[4]; } c; c.w = u;
    __hip_fp8_e4m3 t0, t1, t2, t3;
    t0.__x = c.b[0]; t1.__x = c.b[1]; t2.__x = c.b[2]; t3.__x = c.b[3];
    return make_float4((float)t0, (float)t1, (float)t2, (float)t3);
}

// ------- K1: per-(chunk,slice) LDS histogram; R-half and S-half in one grid ----
__global__ __launch_bounds__(512) void csr_hist_both(
    const int* __restrict__ receivers, const int* __restrict__ senders,
    unsigned int* __restrict__ histR_g, unsigned int* __restrict__ histS_g)
{
    __shared__ unsigned int hist[CHUNKW];   // 50 KB
    int b = blockIdx.x;
    int isS = (b >= NSLICE * NCHUNK);
    int bb = b - isS * NSLICE * NCHUNK;
    const int* idx = isS ? senders : receivers;
    unsigned int* outg = (isS ? histS_g : histR_g) + (size_t)bb * CHUNKW;
    int c = bb & (NCHUNK - 1), s = bb >> 2;
    int t = threadIdx.x;
    for (int w = t; w < CHUNKW; w += 512) hist[w] = 0;
    __syncthreads();
    int base = s * SLICE_E;
    int lo = c * CHUNKN;
    for (int e = base + t; e < base + SLICE_E; e += 512) {
        unsigned int rl = (unsigned int)(idx[e] - lo);
        if (rl < CHUNKN) atomicAdd(&hist[rl >> 1], (rl & 1) ? 65536u : 1u);
    }
    __syncthreads();
    for (int w = t; w < CHUNKW; w += 512) outg[w] = hist[w];
}

// ------ K2: scan slice-partials -> offsets + padded cnt + real cnt + inv ------
__global__ __launch_bounds__(256) void csr_scan_blocks(
    const unsigned int* __restrict__ histR_g, const unsigned int* __restrict__ histS_g,
    unsigned short* __restrict__ blockoffR, int* __restrict__ cntPad,
    int* __restrict__ cntReal, float* __restrict__ inv_r, float* __restrict__ inv_s)
{
    int tid = blockIdx.x * blockDim.x + threadIdx.x;
    if (tid >= NCHUNK * CHUNKW) return;
    int c = tid / CHUNKW, w = tid - c * CHUNKW;
    int node = c * CHUNKN + 2 * w;
    unsigned int runLo = 0, runHi = 0;
#pragma unroll 8
    for (int s = 0; s < NSLICE; s++) {
        unsigned int v = histR_g[(size_t)(s * NCHUNK + c) * CHUNKW + w];
        *(unsigned int*)&blockoffR[(size_t)s * N_NODES + node] =
            (runLo & 0xffffu) | (runHi << 16);
        runLo += v & 0xffffu; runHi += v >> 16;
    }
    ((int2*)cntReal)[node >> 1] = make_int2((int)runLo, (int)runHi);
    ((int2*)cntPad)[node >> 1] =
        make_int2((int)((runLo + 7u) & ~7u), (int)((runHi + 7u) & ~7u));
    ((float2*)inv_r)[node >> 1] =
        make_float2(rsqrtf((float)(runLo + 1)), rsqrtf((float)(runHi + 1)));
    runLo = runHi = 0;
#pragma unroll 8
    for (int s = 0; s < NSLICE; s++) {
        unsigned int v = histS_g[(size_t)(s * NCHUNK + c) * CHUNKW + w];
        runLo += v & 0xffffu; runHi += v >> 16;
    }
    ((float2*)inv_s)[node >> 1] =
        make_float2(rsqrtf((float)(runLo + 1)), rsqrtf((float)(runHi + 1)));
}

// ---------------- exclusive scan of padded counts -> row_ptr ----------------
__global__ __launch_bounds__(256) void scan_blocksum(
    const int* __restrict__ cnt, int* __restrict__ partial)
{
    __shared__ int sred[256];
    int b = blockIdx.x, t = threadIdx.x;
    int base = b * 1024 + t * 4;
    int s = 0;
#pragma unroll
    for (int j = 0; j < 4; j++) {
        int i = base + j;
        s += (i < N_NODES) ? cnt[i] : 0;
    }
    sred[t] = s;
    __syncthreads();
    for (int off = 128; off > 0; off >>= 1) {
        if (t < off) sred[t] += sred[t + off];
        __syncthreads();
    }
    if (t == 0) partial[b] = sred[0];
}

__global__ __launch_bounds__(128) void scan_partials_par(int* partial, int nblk)
{
    __shared__ int lds[128];
    int t = threadIdx.x;
    int v = (t < nblk) ? partial[t] : 0;
    lds[t] = v;
    __syncthreads();
    for (int off = 1; off < 128; off <<= 1) {
        int add = (t >= off) ? lds[t - off] : 0;
        __syncthreads();
        lds[t] += add;
        __syncthreads();
    }
    if (t < nblk) partial[t] = lds[t] - v;   // exclusive
}

// scan_final also writes the pad slots of col (zero-row index N_NODES)
__global__ __launch_bounds__(256) void scan_final(
    const int* __restrict__ cnt, const int* __restrict__ cntReal,
    const int* __restrict__ partial, int* __restrict__ row_ptr,
    int* __restrict__ col)
{
    __shared__ int lds[256];
    int b = blockIdx.x, t = threadIdx.x;
    int base = b * 1024 + t * 4;
    int v[4]; int s = 0;
#pragma unroll
    for (int j = 0; j < 4; j++) {
        int i = base + j;
        v[j] = (i < N_NODES) ? cnt[i] : 0;
        s += v[j];
    }
    lds[t] = s;
    __syncthreads();
    for (int off = 1; off < 256; off <<= 1) {
        int add = (t >= off) ? lds[t - off] : 0;
        __syncthreads();
        lds[t] += add;
        __syncthreads();
    }
    int run = lds[t] - s + partial[b];
#pragma unroll
    for (int j = 0; j < 4; j++) {
        int i = base + j;
        if (i < N_NODES) {
            row_ptr[i] = run;
            int real = cntReal[i];
            for (int k = real; k < v[j]; k++) col[run + k] = N_NODES;
            run += v[j];
            if (i == N_NODES - 1) row_ptr[N_NODES] = run;
        }
    }
}

// ---------------- K3: scatter with LDS local ranks (no global atomics) --------
__global__ __launch_bounds__(512) void csr_scatter(
    const int* __restrict__ senders, const int* __restrict__ receivers,
    const int* __restrict__ row_ptr, const unsigned short* __restrict__ blockoffR,
    int* __restrict__ col)
{
    __shared__ unsigned int lrank[CHUNKW];   // 50 KB
    int c = blockIdx.x & (NCHUNK - 1), s = blockIdx.x >> 2;
    int t = threadIdx.x;
    for (int w = t; w < CHUNKW; w += 512) lrank[w] = 0;
    __syncthreads();
    int base = s * SLICE_E;
    int lo = c * CHUNKN;
    const unsigned short* boff = blockoffR + (size_t)s * N_NODES;
    for (int e = base + t; e < base + SLICE_E; e += 512) {
        int r  = receivers[e];
        int sd = senders[e];
        unsigned int rl = (unsigned int)(r - lo);
        if (rl < CHUNKN) {
            unsigned int old = atomicAdd(&lrank[rl >> 1], (rl & 1) ? 65536u : 1u);
            unsigned int lr = (rl & 1) ? (old >> 16) : (old & 0xffffu);
            col[row_ptr[r] + (int)boff[r] + (int)lr] = sd;
        }
    }
}

// ---------------- embed: xb = bf16(nodes @ W_embed + b_embed) + zero row ------
__global__ __launch_bounds__(256) void embed_kernel(
    const float* __restrict__ nodes, const float* __restrict__ We,
    const float* __restrict__ be, bf16* __restrict__ xb, unsigned char* __restrict__ h8)
{
    int tid = blockIdx.x * blockDim.x + threadIdx.x;   // (node, col-chunk of 8)
    if (tid < 4) {   // zero row h8[N_NODES] for padded-CSR gathers
        uint4 z = {};
        *(uint4*)&h8[(size_t)N_NODES * 64 + tid * 16] = z;
    }
    if (tid >= N_NODES * 8) return;
    int i = tid >> 3, cc = tid & 7;
    float n0 = nodes[i * 3 + 0], n1 = nodes[i * 3 + 1], n2 = nodes[i * 3 + 2];
    union { bf16x8 v; bf16 h[8]; } pk;
#pragma unroll
    for (int k = 0; k < 8; k++) {
        int d = cc * 8 + k;
        float acc = be[d] + n0 * We[0 * 64 + d] + n1 * We[1 * 64 + d] + n2 * We[2 * 64 + d];
        pk.h[k] = __float2bfloat16(acc);
    }
    *(bf16x8*)&xb[(size_t)i * 64 + cc * 8] = pk.v;
}

// ---------------- W fragment pre-pack (f32 -> bf16, MFMA frag order) ----------
__global__ __launch_bounds__(256) void wfrag_kernel(
    const float* __restrict__ W0, const float* __restrict__ W1,
    bf16* __restrict__ frags)
{
    int tid = blockIdx.x * blockDim.x + threadIdx.x;
    if (tid >= 8192) return;
    int j    = tid & 7;
    int lane = (tid >> 3) & 63;
    int c    = (tid >> 9) & 1;
    int nt   = (tid >> 10) & 3;
    int L    = (tid >> 12) & 1;
    int g = lane >> 4, q = lane & 15;
    int k = c * 32 + g * 8 + j;
    int colIdx = nt * 16 + q;
    const float* W = L ? W1 : W0;
    frags[tid] = __float2bfloat16(W[k * 64 + colIdx]);
}

// ------ MFMA 2-layer MLP (+ inv_sqrt_s epilogue), bf16 compute, fp8 h out -----
__global__ __launch_bounds__(256) void mlp_mfma(
    const bf16* __restrict__ xb, unsigned char* __restrict__ h8,
    const bf16* __restrict__ wfrag,
    const float* __restrict__ b0, const float* __restrict__ b1,
    const float* __restrict__ inv_s)
{
    __shared__ char lds_raw[4][2048];
    int t = threadIdx.x;
    int w = t >> 6, lane = t & 63;
    int g = lane >> 4, q = lane & 15;
    char* myLds = lds_raw[w];

    bf16x8 wf[2][4][2];
#pragma unroll
    for (int L = 0; L < 2; L++)
#pragma unroll
        for (int nt = 0; nt < 4; nt++)
#pragma unroll
            for (int c = 0; c < 2; c++)
                wf[L][nt][c] = *(const bf16x8*)&wfrag[((((L * 4 + nt) * 2 + c) * 64) + lane) * 8];

    float bias0[4], bias1[4];
#pragma unroll
    for (int nt = 0; nt < 4; nt++) {
        bias0[nt] = b0[nt * 16 + q];
        bias1[nt] = b1[nt * 16 + q];
    }

    const int NTILES = N_NODES / 16;  // 6250
    for (int tile = blockIdx.x * 4 + w; tile < NTILES; tile += gridDim.x * 4) {
        int nodeBase = tile * 16;

        bf16x8 a0[2];
#pragma unroll
        for (int c = 0; c < 2; c++)
            a0[c] = *(const bf16x8*)&xb[(size_t)(nodeBase + q) * 64 + c * 32 + g * 8];

        f32x4 acc[4];
#pragma unroll
        for (int nt = 0; nt < 4; nt++) {
            acc[nt] = (f32x4){bias0[nt], bias0[nt], bias0[nt], bias0[nt]};
            acc[nt] = __builtin_amdgcn_mfma_f32_16x16x32_bf16(a0[0], wf[0][nt][0], acc[nt], 0, 0, 0);
            acc[nt] = __builtin_amdgcn_mfma_f32_16x16x32_bf16(a0[1], wf[0][nt][1], acc[nt], 0, 0, 0);
        }
#pragma unroll
        for (int nt = 0; nt < 4; nt++)
#pragma unroll
            for (int r = 0; r < 4; r++) {
                float v = fmaxf(acc[nt][r], 0.f);
                int node = g * 4 + r;
                int byte = ((node * 128 + (nt * 16 + q) * 2)) ^ ((node & 7) << 4);
                *(bf16*)(myLds + byte) = __float2bfloat16(v);
            }
        bf16x8 a1[2];
#pragma unroll
        for (int c = 0; c < 2; c++) {
            int byte = (q * 128 + c * 64 + g * 16) ^ ((q & 7) << 4);
            a1[c] = *(const bf16x8*)(myLds + byte);
        }

        f32x4 acc1[4];
#pragma unroll
        for (int nt = 0; nt < 4; nt++) {
            acc1[nt] = (f32x4){bias1[nt], bias1[nt], bias1[nt], bias1[nt]};
            acc1[nt] = __builtin_amdgcn_mfma_f32_16x16x32_bf16(a1[0], wf[1][nt][0], acc1[nt], 0, 0, 0);
            acc1[nt] = __builtin_amdgcn_mfma_f32_16x16x32_bf16(a1[1], wf[1][nt][1], acc1[nt], 0, 0, 0);
        }
        float is[4];
#pragma unroll
        for (int r = 0; r < 4; r++) is[r] = inv_s[nodeBase + g * 4 + r];
#pragma unroll
        for (int nt = 0; nt < 4; nt++)
#pragma unroll
            for (int r = 0; r < 4; r++) {
                float v = fmaxf(acc1[nt][r], 0.f) * is[r];
                int node = g * 4 + r;
                int byte = ((node * 128 + (nt * 16 + q) * 2)) ^ ((node & 7) << 4);
                *(bf16*)(myLds + byte) = __float2bfloat16(v);
            }
        // linear read-back, convert to fp8, single 16B store per lane
        union { uint4 u4; unsigned char b[16]; } pk8;
#pragma unroll
        for (int half = 0; half < 2; half++) {
            int byteL = lane * 32 + half * 16;
            int node = byteL >> 7;
            bf16x8 v = *(const bf16x8*)(myLds + (byteL ^ ((node & 7) << 4)));
#pragma unroll
            for (int k = 0; k < 8; k++) {
                __hip_fp8_e4m3 f8(bf2f(v[k]));
                pk8.b[half * 8 + k] = f8.__x;
            }
        }
        *(uint4*)&h8[(size_t)nodeBase * 64 + lane * 16] = pk8.u4;
    }
}

// --- gather-aggregate: fp8 h, 4-slot lanes, u32 gathers, prefetched col, LN ---
__global__ __launch_bounds__(256) void agg_ln_kernel(
    const unsigned char* __restrict__ h8, bf16* __restrict__ xb,
    const int* __restrict__ row_ptr, const int* __restrict__ col,
    const float* __restrict__ inv_r,
    const float* __restrict__ ln_scale, const float* __restrict__ ln_bias)
{
    int t = threadIdx.x;
    int lane = t & 63;
    int sub = lane >> 4;          // edge-slot 0..3
    int q = lane & 15;            // this lane covers columns 4q..4q+3
    float4 lnsv = *(const float4*)&ln_scale[4 * q];
    float4 lnbv = *(const float4*)&ln_bias[4 * q];
    int gw = __builtin_amdgcn_readfirstlane((blockIdx.x * blockDim.x + t) >> 6);
    int nwaves = (gridDim.x * blockDim.x) >> 6;
    for (int i = gw; i < N_NODES; i += nwaves) {
        float a0 = 0.f, a1 = 0.f, a2 = 0.f, a3 = 0.f;
        // self edge (inv_s already folded into h); count once via sub==0
        unsigned int su = *(const unsigned int*)&h8[(size_t)i * 64 + 4 * q];
        if (sub == 0) {
            float4 s4 = fp8x4(su);
            a0 = s4.x; a1 = s4.y; a2 = s4.z; a3 = s4.w;
        }
        int beg = row_ptr[i], end = row_ptr[i + 1];   // padded: (end-beg) % 8 == 0
        int2 ci = *(const int2*)&col[beg + 2 * sub];
        for (int e = beg; e < end; e += 8) {
            int ne = e + 8;
            int2 cn = (ne < end) ? *(const int2*)&col[ne + 2 * sub]
                                 : make_int2(N_NODES, N_NODES);
            unsigned int u0 = *(const unsigned int*)&h8[(size_t)ci.x * 64 + 4 * q];
            unsigned int u1 = *(const unsigned int*)&h8[(size_t)ci.y * 64 + 4 * q];
            float4 f0 = fp8x4(u0);
            float4 f1 = fp8x4(u1);
            a0 += f0.x + f1.x;
            a1 += f0.y + f1.y;
            a2 += f0.z + f1.z;
            a3 += f0.w + f1.w;
            ci = cn;
        }
        // merge the 4 edge-slot partials (bits 4,5 of lane)
        a0 += __shfl_xor(a0, 16); a0 += __shfl_xor(a0, 32);
        a1 += __shfl_xor(a1, 16); a1 += __shfl_xor(a1, 32);
        a2 += __shfl_xor(a2, 16); a2 += __shfl_xor(a2, 32);
        a3 += __shfl_xor(a3, 16); a3 += __shfl_xor(a3, 32);
        float ir = inv_r[i];
        uint2 xu = *(const uint2*)&xb[(size_t)i * 64 + 4 * q];
        float y0 = a0 * ir + blo(xu.x);
        float y1 = a1 * ir + bhi(xu.x);
        float y2 = a2 * ir + blo(xu.y);
        float y3 = a3 * ir + bhi(xu.y);
        // LayerNorm over 64 cols = 4 per lane x 16 lanes (duplicated across subs)
        float sum = (y0 + y1) + (y2 + y3);
#pragma unroll
        for (int m = 1; m < 16; m <<= 1) sum += __shfl_xor(sum, m);
        float mu = sum * (1.f / 64.f);
        float d0 = y0 - mu, d1 = y1 - mu, d2 = y2 - mu, d3 = y3 - mu;
        float vs = (d0 * d0 + d1 * d1) + (d2 * d2 + d3 * d3);
#pragma unroll
        for (int m = 1; m < 16; m <<= 1) vs += __shfl_xor(vs, m);
        float var = vs * (1.f / 64.f);
        float rr = rsqrtf(var + 1e-6f);
        float o0 = d0 * rr * lnsv.x + lnbv.x;
        float o1 = d1 * rr * lnsv.y + lnbv.y;
        float o2 = d2 * rr * lnsv.z + lnbv.z;
        float o3 = d3 * rr * lnsv.w + lnbv.w;
        if (sub == 0) {
            union { uint2 u; bf16 h4[4]; } pk;
            pk.h4[0] = __float2bfloat16(o0);
            pk.h4[1] = __float2bfloat16(o1);
            pk.h4[2] = __float2bfloat16(o2);
            pk.h4[3] = __float2bfloat16(o3);
            *(uint2*)&xb[(size_t)i * 64 + 4 * q] = pk.u;
        }
    }
}

// ---------------- pool stage 1: partial sums, vectorized bf16x8 loads ---------
__global__ __launch_bounds__(256) void pool_stage1(
    const bf16* __restrict__ xb, const int* __restrict__ n_node,
    float* __restrict__ partialP)   // [N_GRAPH][POOL_PB][64]
{
    __shared__ float red[32][8][8];  // 8 KB
    int b = blockIdx.x;
    int g = b >> 3, sub = b & 7;
    int t = threadIdx.x;
    int start = 0;
    for (int j = 0; j < g; j++) start += n_node[j];
    int cnt = n_node[g];
    int jbeg = (int)(((long long)cnt * sub) / POOL_PB);
    int jend = (int)(((long long)cnt * (sub + 1)) / POOL_PB);
    int rg = t >> 3, cc = t & 7;
    float acc[8];
#pragma unroll
    for (int k = 0; k < 8; k++) acc[k] = 0.f;
    for (int j = jbeg + rg; j < jend; j += 32) {
        bf16x8 v = *(const bf16x8*)&xb[(size_t)(start + j) * 64 + cc * 8];
#pragma unroll
        for (int k = 0; k < 8; k++) acc[k] += bf2f(v[k]);
    }
#pragma unroll
    for (int k = 0; k < 8; k++) red[rg][cc][k] = acc[k];
    __syncthreads();
    if (t < 64) {
        float s = 0.f;
#pragma unroll 8
        for (int r = 0; r < 32; r++) s += red[r][t >> 3][t & 7];
        partialP[((size_t)g * POOL_PB + sub) * 64 + t] = s;
    }
}

// ---------------- pool stage 2: reduce partials + mean + decoder GEMV ---------
__global__ __launch_bounds__(64) void pool_stage2(
    const float* __restrict__ partialP, const int* __restrict__ n_node,
    const float* __restrict__ Wg, const float* __restrict__ bg,
    float* __restrict__ out)
{
    __shared__ float pd[64];
    int g = blockIdx.x;
    int t = threadIdx.x;
    float s = 0.f;
#pragma unroll
    for (int p = 0; p < POOL_PB; p++) s += partialP[((size_t)g * POOL_PB + p) * 64 + t];
    int cnt = n_node[g];
    pd[t] = s / fmaxf((float)cnt, 1.f);
    __syncthreads();
    if (t < OUT_G) {
        float v = bg[t];
#pragma unroll 16
        for (int dd = 0; dd < 64; dd++) v += pd[dd] * Wg[dd * OUT_G + t];
        out[g * OUT_G + t] = v;
    }
}

extern "C" void kernel_launch(void* const* d_in, const int* in_sizes, int n_in,
                              void* d_out, int out_size, void* d_ws, size_t ws_size,
                              hipStream_t stream) {
    const float* nodes    = (const float*)d_in[0];
    const int*   senders  = (const int*)d_in[1];
    const int*   receivers= (const int*)d_in[2];
    const int*   n_node   = (const int*)d_in[3];
    const float* W_embed  = (const float*)d_in[4];
    const float* b_embed  = (const float*)d_in[5];
    const float* W_mlp0   = (const float*)d_in[6];
    const float* b_mlp0   = (const float*)d_in[7];
    const float* W_mlp1   = (const float*)d_in[8];
    const float* b_mlp1   = (const float*)d_in[9];
    const float* ln_scale = (const float*)d_in[10];
    const float* ln_bias  = (const float*)d_in[11];
    const float* W_glob   = (const float*)d_in[12];
    const float* b_glob   = (const float*)d_in[13];
    float* out = (float*)d_out;

    // workspace layout (16B-aligned pieces)
    char* ws = (char*)d_ws;
    bf16*  xb     = (bf16*)ws;    ws += (size_t)N_NODES * 64 * 2;        // 12.8 MB
    unsigned char* h8 = (unsigned char*)ws; ws += (size_t)(N_NODES + 1) * 64; // 6.4 MB + zero row
    unsigned int* histS_g = (unsigned int*)ws; ws += (size_t)NSLICE * NCHUNK * CHUNKW * 4; // 12.8 MB
    unsigned int* histR_g = (unsigned int*)ws; ws += (size_t)NSLICE * NCHUNK * CHUNKW * 4; // 12.8 MB
    float* inv_s  = (float*)ws;   ws += (size_t)N_NODES * 4;
    float* inv_r  = (float*)ws;   ws += (size_t)N_NODES * 4;
    int*   cntPad = (int*)ws;     ws += (size_t)N_NODES * 4;
    int*   cntReal= (int*)ws;     ws += (size_t)N_NODES * 4;
    int*   row_ptr= (int*)ws;     ws += (size_t)(N_NODES + 4) * 4;
    int*   col    = (int*)ws;     ws += (size_t)COL_CAP * 4;             // 9.2 MB
    int*   partial= (int*)ws;     ws += 256 * 4;
    bf16*  wfrag  = (bf16*)ws;    ws += 8192 * 2;
    float* partialP = (float*)ws; ws += (size_t)N_GRAPH * POOL_PB * 64 * 4;

    // blockoffR aliases xb (dead until embed writes xb)
    unsigned short* blockoffR = (unsigned short*)xb;  // 12.8 MB

    const int nblk_scan = (N_NODES + 1023) / 1024;  // 98

    // ---- CSR build (no global atomics), padded rows ----
    csr_hist_both<<<2 * NSLICE * NCHUNK, 512, 0, stream>>>(receivers, senders, histR_g, histS_g);
    csr_scan_blocks<<<(NCHUNK * CHUNKW + 255) / 256, 256, 0, stream>>>(
        histR_g, histS_g, blockoffR, cntPad, cntReal, inv_r, inv_s);
    scan_blocksum<<<nblk_scan, 256, 0, stream>>>(cntPad, partial);
    scan_partials_par<<<1, 128, 0, stream>>>(partial, nblk_scan);
    scan_final<<<nblk_scan, 256, 0, stream>>>(cntPad, cntReal, partial, row_ptr, col);
    csr_scatter<<<NSLICE * NCHUNK, 512, 0, stream>>>(senders, receivers, row_ptr, blockoffR, col);

    // ---- embed (after CSR temporaries are dead) ----
    embed_kernel<<<(N_NODES * 8 + 255) / 256, 256, 0, stream>>>(nodes, W_embed, b_embed, xb, h8);
    wfrag_kernel<<<32, 256, 0, stream>>>(W_mlp0, W_mlp1, wfrag);

    for (int step = 0; step < N_STEPS; ++step) {
        mlp_mfma<<<1563, 256, 0, stream>>>(xb, h8, wfrag, b_mlp0, b_mlp1, inv_s);
        agg_ln_kernel<<<4096, 256, 0, stream>>>(h8, xb, row_ptr, col, inv_r, ln_scale, ln_bias);
    }

    pool_stage1<<<N_GRAPH * POOL_PB, 256, 0, stream>>>(xb, n_node, partialP);
    pool_stage2<<<N_GRAPH, 64, 0, stream>>>(partialP, n_node, W_glob, b_glob, out);
}

// Round 14
// 336.671 us; speedup vs baseline: 1.2616x; 1.0328x over previous
//
#include <hip/hip_runtime.h>
#include <hip/hip_bf16.h>
#include <hip/hip_fp8.h>

#define N_NODES 100000
#define N_EDGES 1600000
#define LATENT 64
#define N_GRAPH 100
#define OUT_G 16
#define N_STEPS 3

// CSR-build geometry (u8-packed histograms: 4 node-counts per u32 word)
#define NCHUNK 2
#define CHUNKN 50000            // nodes per chunk
#define CHUNKW 12500            // packed u8x4 words per chunk (50 KB LDS)
#define NSLICE 128
#define SLICE_E 12500           // edges per slice (128*12500 = 1.6M)

#define POOL_PB 8               // stage-1 blocks per graph
#define COL_CAP (N_EDGES + 7 * N_NODES + 64)   // padded CSR capacity

using bf16 = __hip_bfloat16;
using bf16x8 = __attribute__((ext_vector_type(8))) short;
using f32x4  = __attribute__((ext_vector_type(4))) float;

__device__ __forceinline__ float blo(unsigned int u) {
    union { unsigned int i; float f; } v; v.i = u << 16; return v.f;
}
__device__ __forceinline__ float bhi(unsigned int u) {
    union { unsigned int i; float f; } v; v.i = u & 0xffff0000u; return v.f;
}
__device__ __forceinline__ float bf2f(short s) {
    union { unsigned int i; float f; } v; v.i = ((unsigned int)(unsigned short)s) << 16; return v.f;
}
// 4 packed fp8 e4m3 -> 4 floats (native cvt on gfx950)
__device__ __forceinline__ float4 fp8x4(unsigned int u) {
    union { unsigned int w; __hip_fp8_storage_t b[4]; } c; c.w = u;
    __hip_fp8_e4m3 t0, t1, t2, t3;
    t0.__x = c.b[0]; t1.__x = c.b[1]; t2.__x = c.b[2]; t3.__x = c.b[3];
    return make_float4((float)t0, (float)t1, (float)t2, (float)t3);
}

// ------- K1: per-(chunk,slice) u8-packed LDS histogram; R and S in one grid ---
__global__ __launch_bounds__(512) void csr_hist_both(
    const int* __restrict__ receivers, const int* __restrict__ senders,
    unsigned int* __restrict__ histR_g, unsigned int* __restrict__ histS_g)
{
    __shared__ unsigned int hist[CHUNKW];   // 50 KB, u8 x4 per word
    int b = blockIdx.x;
    int isS = (b >= NSLICE * NCHUNK);
    int bb = b - isS * NSLICE * NCHUNK;
    const int* idx = isS ? senders : receivers;
    unsigned int* outg = (isS ? histS_g : histR_g) + (size_t)bb * CHUNKW;
    int c = bb & (NCHUNK - 1), s = bb >> 1;
    int t = threadIdx.x;
    for (int w = t; w < CHUNKW; w += 512) hist[w] = 0;
    __syncthreads();
    int base = s * SLICE_E;
    int lo = c * CHUNKN;
    for (int e = base + t; e < base + SLICE_E; e += 512) {
        unsigned int rl = (unsigned int)(idx[e] - lo);
        if (rl < CHUNKN) atomicAdd(&hist[rl >> 2], 1u << ((rl & 3) * 8));
    }
    __syncthreads();
    for (int w = t; w < CHUNKW; w += 512) outg[w] = hist[w];
}

// ------ K2: scan slice-partials -> u8 offsets + padded cnt + real cnt + inv ---
__global__ __launch_bounds__(256) void csr_scan_blocks(
    const unsigned int* __restrict__ histR_g, const unsigned int* __restrict__ histS_g,
    unsigned char* __restrict__ blockoffR, int* __restrict__ cntPad,
    int* __restrict__ cntReal, float* __restrict__ inv_r, float* __restrict__ inv_s)
{
    int tid = blockIdx.x * blockDim.x + threadIdx.x;
    if (tid >= NCHUNK * CHUNKW) return;
    int c = tid / CHUNKW, w = tid - c * CHUNKW;
    int node = c * CHUNKN + 4 * w;
    unsigned int r0 = 0, r1 = 0, r2 = 0, r3 = 0;
#pragma unroll 8
    for (int s = 0; s < NSLICE; s++) {
        unsigned int v = histR_g[(size_t)(s * NCHUNK + c) * CHUNKW + w];
        *(unsigned int*)&blockoffR[(size_t)s * N_NODES + node] =
            r0 | (r1 << 8) | (r2 << 16) | (r3 << 24);
        r0 += v & 0xffu; r1 += (v >> 8) & 0xffu;
        r2 += (v >> 16) & 0xffu; r3 += (v >> 24) & 0xffu;
    }
    ((int4*)cntReal)[node >> 2] = make_int4((int)r0, (int)r1, (int)r2, (int)r3);
    ((int4*)cntPad)[node >> 2] = make_int4(
        (int)((r0 + 7u) & ~7u), (int)((r1 + 7u) & ~7u),
        (int)((r2 + 7u) & ~7u), (int)((r3 + 7u) & ~7u));
    ((float4*)inv_r)[node >> 2] = make_float4(
        rsqrtf((float)(r0 + 1)), rsqrtf((float)(r1 + 1)),
        rsqrtf((float)(r2 + 1)), rsqrtf((float)(r3 + 1)));
    r0 = r1 = r2 = r3 = 0;
#pragma unroll 8
    for (int s = 0; s < NSLICE; s++) {
        unsigned int v = histS_g[(size_t)(s * NCHUNK + c) * CHUNKW + w];
        r0 += v & 0xffu; r1 += (v >> 8) & 0xffu;
        r2 += (v >> 16) & 0xffu; r3 += (v >> 24) & 0xffu;
    }
    ((float4*)inv_s)[node >> 2] = make_float4(
        rsqrtf((float)(r0 + 1)), rsqrtf((float)(r1 + 1)),
        rsqrtf((float)(r2 + 1)), rsqrtf((float)(r3 + 1)));
}

// ---------------- exclusive scan of padded counts -> row_ptr ----------------
__global__ __launch_bounds__(256) void scan_blocksum(
    const int* __restrict__ cnt, int* __restrict__ partial)
{
    __shared__ int sred[256];
    int b = blockIdx.x, t = threadIdx.x;
    int base = b * 1024 + t * 4;
    int s = 0;
#pragma unroll
    for (int j = 0; j < 4; j++) {
        int i = base + j;
        s += (i < N_NODES) ? cnt[i] : 0;
    }
    sred[t] = s;
    __syncthreads();
    for (int off = 128; off > 0; off >>= 1) {
        if (t < off) sred[t] += sred[t + off];
        __syncthreads();
    }
    if (t == 0) partial[b] = sred[0];
}

__global__ __launch_bounds__(128) void scan_partials_par(int* partial, int nblk)
{
    __shared__ int lds[128];
    int t = threadIdx.x;
    int v = (t < nblk) ? partial[t] : 0;
    lds[t] = v;
    __syncthreads();
    for (int off = 1; off < 128; off <<= 1) {
        int add = (t >= off) ? lds[t - off] : 0;
        __syncthreads();
        lds[t] += add;
        __syncthreads();
    }
    if (t < nblk) partial[t] = lds[t] - v;   // exclusive
}

// scan_final also writes the pad slots of col (zero-row index N_NODES)
__global__ __launch_bounds__(256) void scan_final(
    const int* __restrict__ cnt, const int* __restrict__ cntReal,
    const int* __restrict__ partial, int* __restrict__ row_ptr,
    int* __restrict__ col)
{
    __shared__ int lds[256];
    int b = blockIdx.x, t = threadIdx.x;
    int base = b * 1024 + t * 4;
    int v[4]; int s = 0;
#pragma unroll
    for (int j = 0; j < 4; j++) {
        int i = base + j;
        v[j] = (i < N_NODES) ? cnt[i] : 0;
        s += v[j];
    }
    lds[t] = s;
    __syncthreads();
    for (int off = 1; off < 256; off <<= 1) {
        int add = (t >= off) ? lds[t - off] : 0;
        __syncthreads();
        lds[t] += add;
        __syncthreads();
    }
    int run = lds[t] - s + partial[b];
#pragma unroll
    for (int j = 0; j < 4; j++) {
        int i = base + j;
        if (i < N_NODES) {
            row_ptr[i] = run;
            int real = cntReal[i];
            for (int k = real; k < v[j]; k++) col[run + k] = N_NODES;
            run += v[j];
            if (i == N_NODES - 1) row_ptr[N_NODES] = run;
        }
    }
}

// ------- K3: scatter with u8-packed LDS local ranks (no global atomics) -------
__global__ __launch_bounds__(512) void csr_scatter(
    const int* __restrict__ senders, const int* __restrict__ receivers,
    const int* __restrict__ row_ptr, const unsigned char* __restrict__ blockoffR,
    int* __restrict__ col)
{
    __shared__ unsigned int lrank[CHUNKW];   // 50 KB, u8 x4 per word
    int c = blockIdx.x & (NCHUNK - 1), s = blockIdx.x >> 1;
    int t = threadIdx.x;
    for (int w = t; w < CHUNKW; w += 512) lrank[w] = 0;
    __syncthreads();
    int base = s * SLICE_E;
    int lo = c * CHUNKN;
    const unsigned char* boff = blockoffR + (size_t)s * N_NODES;
    for (int e = base + t; e < base + SLICE_E; e += 512) {
        int r  = receivers[e];
        int sd = senders[e];
        unsigned int rl = (unsigned int)(r - lo);
        if (rl < CHUNKN) {
            unsigned int sh = (rl & 3) * 8;
            unsigned int old = atomicAdd(&lrank[rl >> 2], 1u << sh);
            unsigned int lr = (old >> sh) & 0xffu;
            col[row_ptr[r] + (int)boff[r] + (int)lr] = sd;
        }
    }
}

// ---------------- embed: xb = bf16(nodes @ W_embed + b_embed) + zero row ------
__global__ __launch_bounds__(256) void embed_kernel(
    const float* __restrict__ nodes, const float* __restrict__ We,
    const float* __restrict__ be, bf16* __restrict__ xb, unsigned char* __restrict__ h8)
{
    int tid = blockIdx.x * blockDim.x + threadIdx.x;   // (node, col-chunk of 8)
    if (tid < 4) {   // zero row h8[N_NODES] for padded-CSR gathers
        uint4 z = {};
        *(uint4*)&h8[(size_t)N_NODES * 64 + tid * 16] = z;
    }
    if (tid >= N_NODES * 8) return;
    int i = tid >> 3, cc = tid & 7;
    float n0 = nodes[i * 3 + 0], n1 = nodes[i * 3 + 1], n2 = nodes[i * 3 + 2];
    union { bf16x8 v; bf16 h[8]; } pk;
#pragma unroll
    for (int k = 0; k < 8; k++) {
        int d = cc * 8 + k;
        float acc = be[d] + n0 * We[0 * 64 + d] + n1 * We[1 * 64 + d] + n2 * We[2 * 64 + d];
        pk.h[k] = __float2bfloat16(acc);
    }
    *(bf16x8*)&xb[(size_t)i * 64 + cc * 8] = pk.v;
}

// ---------------- W fragment pre-pack (f32 -> bf16, MFMA frag order) ----------
__global__ __launch_bounds__(256) void wfrag_kernel(
    const float* __restrict__ W0, const float* __restrict__ W1,
    bf16* __restrict__ frags)
{
    int tid = blockIdx.x * blockDim.x + threadIdx.x;
    if (tid >= 8192) return;
    int j    = tid & 7;
    int lane = (tid >> 3) & 63;
    int c    = (tid >> 9) & 1;
    int nt   = (tid >> 10) & 3;
    int L    = (tid >> 12) & 1;
    int g = lane >> 4, q = lane & 15;
    int k = c * 32 + g * 8 + j;
    int colIdx = nt * 16 + q;
    const float* W = L ? W1 : W0;
    frags[tid] = __float2bfloat16(W[k * 64 + colIdx]);
}

// ------ MFMA 2-layer MLP (+ inv_sqrt_s epilogue), bf16 compute, fp8 h out -----
__global__ __launch_bounds__(256) void mlp_mfma(
    const bf16* __restrict__ xb, unsigned char* __restrict__ h8,
    const bf16* __restrict__ wfrag,
    const float* __restrict__ b0, const float* __restrict__ b1,
    const float* __restrict__ inv_s)
{
    __shared__ char lds_raw[4][2048];
    int t = threadIdx.x;
    int w = t >> 6, lane = t & 63;
    int g = lane >> 4, q = lane & 15;
    char* myLds = lds_raw[w];

    bf16x8 wf[2][4][2];
#pragma unroll
    for (int L = 0; L < 2; L++)
#pragma unroll
        for (int nt = 0; nt < 4; nt++)
#pragma unroll
            for (int c = 0; c < 2; c++)
                wf[L][nt][c] = *(const bf16x8*)&wfrag[((((L * 4 + nt) * 2 + c) * 64) + lane) * 8];

    float bias0[4], bias1[4];
#pragma unroll
    for (int nt = 0; nt < 4; nt++) {
        bias0[nt] = b0[nt * 16 + q];
        bias1[nt] = b1[nt * 16 + q];
    }

    const int NTILES = N_NODES / 16;  // 6250
    for (int tile = blockIdx.x * 4 + w; tile < NTILES; tile += gridDim.x * 4) {
        int nodeBase = tile * 16;

        bf16x8 a0[2];
#pragma unroll
        for (int c = 0; c < 2; c++)
            a0[c] = *(const bf16x8*)&xb[(size_t)(nodeBase + q) * 64 + c * 32 + g * 8];

        f32x4 acc[4];
#pragma unroll
        for (int nt = 0; nt < 4; nt++) {
            acc[nt] = (f32x4){bias0[nt], bias0[nt], bias0[nt], bias0[nt]};
            acc[nt] = __builtin_amdgcn_mfma_f32_16x16x32_bf16(a0[0], wf[0][nt][0], acc[nt], 0, 0, 0);
            acc[nt] = __builtin_amdgcn_mfma_f32_16x16x32_bf16(a0[1], wf[0][nt][1], acc[nt], 0, 0, 0);
        }
#pragma unroll
        for (int nt = 0; nt < 4; nt++)
#pragma unroll
            for (int r = 0; r < 4; r++) {
                float v = fmaxf(acc[nt][r], 0.f);
                int node = g * 4 + r;
                int byte = ((node * 128 + (nt * 16 + q) * 2)) ^ ((node & 7) << 4);
                *(bf16*)(myLds + byte) = __float2bfloat16(v);
            }
        bf16x8 a1[2];
#pragma unroll
        for (int c = 0; c < 2; c++) {
            int byte = (q * 128 + c * 64 + g * 16) ^ ((q & 7) << 4);
            a1[c] = *(const bf16x8*)(myLds + byte);
        }

        f32x4 acc1[4];
#pragma unroll
        for (int nt = 0; nt < 4; nt++) {
            acc1[nt] = (f32x4){bias1[nt], bias1[nt], bias1[nt], bias1[nt]};
            acc1[nt] = __builtin_amdgcn_mfma_f32_16x16x32_bf16(a1[0], wf[1][nt][0], acc1[nt], 0, 0, 0);
            acc1[nt] = __builtin_amdgcn_mfma_f32_16x16x32_bf16(a1[1], wf[1][nt][1], acc1[nt], 0, 0, 0);
        }
        float is[4];
#pragma unroll
        for (int r = 0; r < 4; r++) is[r] = inv_s[nodeBase + g * 4 + r];
#pragma unroll
        for (int nt = 0; nt < 4; nt++)
#pragma unroll
            for (int r = 0; r < 4; r++) {
                float v = fmaxf(acc1[nt][r], 0.f) * is[r];
                int node = g * 4 + r;
                int byte = ((node * 128 + (nt * 16 + q) * 2)) ^ ((node & 7) << 4);
                *(bf16*)(myLds + byte) = __float2bfloat16(v);
            }
        // linear read-back, convert to fp8, single 16B store per lane
        union { uint4 u4; unsigned char b[16]; } pk8;
#pragma unroll
        for (int half = 0; half < 2; half++) {
            int byteL = lane * 32 + half * 16;
            int node = byteL >> 7;
            bf16x8 v = *(const bf16x8*)(myLds + (byteL ^ ((node & 7) << 4)));
#pragma unroll
            for (int k = 0; k < 8; k++) {
                __hip_fp8_e4m3 f8(bf2f(v[k]));
                pk8.b[half * 8 + k] = f8.__x;
            }
        }
        *(uint4*)&h8[(size_t)nodeBase * 64 + lane * 16] = pk8.u4;
    }
}

// --- gather-aggregate: fp8 h, 2 interleaved rows per wave, padded rows, LN ----
__global__ __launch_bounds__(256) void agg_ln_kernel(
    const unsigned char* __restrict__ h8, bf16* __restrict__ xb,
    const int* __restrict__ row_ptr, const int* __restrict__ col,
    const float* __restrict__ inv_r,
    const float* __restrict__ ln_scale, const float* __restrict__ ln_bias)
{
    int t = threadIdx.x;
    int lane = t & 63;
    int sub = lane >> 4;          // edge-slot 0..3
    int q = lane & 15;            // this lane covers columns 4q..4q+3
    float4 lnsv = *(const float4*)&ln_scale[4 * q];
    float4 lnbv = *(const float4*)&ln_bias[4 * q];
    int gw = __builtin_amdgcn_readfirstlane((blockIdx.x * blockDim.x + t) >> 6);
    int nwaves = (gridDim.x * blockDim.x) >> 6;
    for (int i0 = gw; i0 < N_NODES; i0 += 2 * nwaves) {
        int iA = i0;
        int iB = i0 + nwaves;
        bool hasB = (iB < N_NODES);
        float A0 = 0.f, A1 = 0.f, A2 = 0.f, A3 = 0.f;
        float B0 = 0.f, B1 = 0.f, B2 = 0.f, B3 = 0.f;
        // self edges (inv_s already folded into h)
        unsigned int suA = *(const unsigned int*)&h8[(size_t)iA * 64 + 4 * q];
        unsigned int suB = hasB ? *(const unsigned int*)&h8[(size_t)iB * 64 + 4 * q] : 0u;
        int begA = row_ptr[iA], endA = row_ptr[iA + 1];
        int begB = 0, endB = 0;
        if (hasB) { begB = row_ptr[iB]; endB = row_ptr[iB + 1]; }
        if (sub == 0) {
            float4 sA = fp8x4(suA);
            A0 = sA.x; A1 = sA.y; A2 = sA.z; A3 = sA.w;
            float4 sB = fp8x4(suB);
            B0 = sB.x; B1 = sB.y; B2 = sB.z; B3 = sB.w;
        }
        int eA = begA, eB = begB;
        int2 ciA = (eA < endA) ? *(const int2*)&col[eA + 2 * sub] : make_int2(N_NODES, N_NODES);
        int2 ciB = (eB < endB) ? *(const int2*)&col[eB + 2 * sub] : make_int2(N_NODES, N_NODES);
        while (eA < endA || eB < endB) {           // wave-uniform conditions
            if (eA < endA) {
                int ne = eA + 8;
                int2 cn = (ne < endA) ? *(const int2*)&col[ne + 2 * sub]
                                      : make_int2(N_NODES, N_NODES);
                unsigned int u0 = *(const unsigned int*)&h8[(size_t)ciA.x * 64 + 4 * q];
                unsigned int u1 = *(const unsigned int*)&h8[(size_t)ciA.y * 64 + 4 * q];
                float4 f0 = fp8x4(u0);
                float4 f1 = fp8x4(u1);
                A0 += f0.x + f1.x; A1 += f0.y + f1.y;
                A2 += f0.z + f1.z; A3 += f0.w + f1.w;
                ciA = cn; eA = ne;
            }
            if (eB < endB) {
                int ne = eB + 8;
                int2 cn = (ne < endB) ? *(const int2*)&col[ne + 2 * sub]
                                      : make_int2(N_NODES, N_NODES);
                unsigned int u0 = *(const unsigned int*)&h8[(size_t)ciB.x * 64 + 4 * q];
                unsigned int u1 = *(const unsigned int*)&h8[(size_t)ciB.y * 64 + 4 * q];
                float4 f0 = fp8x4(u0);
                float4 f1 = fp8x4(u1);
                B0 += f0.x + f1.x; B1 += f0.y + f1.y;
                B2 += f0.z + f1.z; B3 += f0.w + f1.w;
                ciB = cn; eB = ne;
            }
        }
        // ---- row A: merge slots, LN, store ----
        A0 += __shfl_xor(A0, 16); A0 += __shfl_xor(A0, 32);
        A1 += __shfl_xor(A1, 16); A1 += __shfl_xor(A1, 32);
        A2 += __shfl_xor(A2, 16); A2 += __shfl_xor(A2, 32);
        A3 += __shfl_xor(A3, 16); A3 += __shfl_xor(A3, 32);
        {
            float ir = inv_r[iA];
            uint2 xu = *(const uint2*)&xb[(size_t)iA * 64 + 4 * q];
            float y0 = A0 * ir + blo(xu.x);
            float y1 = A1 * ir + bhi(xu.x);
            float y2 = A2 * ir + blo(xu.y);
            float y3 = A3 * ir + bhi(xu.y);
            float sum = (y0 + y1) + (y2 + y3);
#pragma unroll
            for (int m = 1; m < 16; m <<= 1) sum += __shfl_xor(sum, m);
            float mu = sum * (1.f / 64.f);
            float d0 = y0 - mu, d1 = y1 - mu, d2 = y2 - mu, d3 = y3 - mu;
            float vs = (d0 * d0 + d1 * d1) + (d2 * d2 + d3 * d3);
#pragma unroll
            for (int m = 1; m < 16; m <<= 1) vs += __shfl_xor(vs, m);
            float rr = rsqrtf(vs * (1.f / 64.f) + 1e-6f);
            if (sub == 0) {
                union { uint2 u; bf16 h4[4]; } pk;
                pk.h4[0] = __float2bfloat16(d0 * rr * lnsv.x + lnbv.x);
                pk.h4[1] = __float2bfloat16(d1 * rr * lnsv.y + lnbv.y);
                pk.h4[2] = __float2bfloat16(d2 * rr * lnsv.z + lnbv.z);
                pk.h4[3] = __float2bfloat16(d3 * rr * lnsv.w + lnbv.w);
                *(uint2*)&xb[(size_t)iA * 64 + 4 * q] = pk.u;
            }
        }
        // ---- row B ----
        if (hasB) {
            B0 += __shfl_xor(B0, 16); B0 += __shfl_xor(B0, 32);
            B1 += __shfl_xor(B1, 16); B1 += __shfl_xor(B1, 32);
            B2 += __shfl_xor(B2, 16); B2 += __shfl_xor(B2, 32);
            B3 += __shfl_xor(B3, 16); B3 += __shfl_xor(B3, 32);
            float ir = inv_r[iB];
            uint2 xu = *(const uint2*)&xb[(size_t)iB * 64 + 4 * q];
            float y0 = B0 * ir + blo(xu.x);
            float y1 = B1 * ir + bhi(xu.x);
            float y2 = B2 * ir + blo(xu.y);
            float y3 = B3 * ir + bhi(xu.y);
            float sum = (y0 + y1) + (y2 + y3);
#pragma unroll
            for (int m = 1; m < 16; m <<= 1) sum += __shfl_xor(sum, m);
            float mu = sum * (1.f / 64.f);
            float d0 = y0 - mu, d1 = y1 - mu, d2 = y2 - mu, d3 = y3 - mu;
            float vs = (d0 * d0 + d1 * d1) + (d2 * d2 + d3 * d3);
#pragma unroll
            for (int m = 1; m < 16; m <<= 1) vs += __shfl_xor(vs, m);
            float rr = rsqrtf(vs * (1.f / 64.f) + 1e-6f);
            if (sub == 0) {
                union { uint2 u; bf16 h4[4]; } pk;
                pk.h4[0] = __float2bfloat16(d0 * rr * lnsv.x + lnbv.x);
                pk.h4[1] = __float2bfloat16(d1 * rr * lnsv.y + lnbv.y);
                pk.h4[2] = __float2bfloat16(d2 * rr * lnsv.z + lnbv.z);
                pk.h4[3] = __float2bfloat16(d3 * rr * lnsv.w + lnbv.w);
                *(uint2*)&xb[(size_t)iB * 64 + 4 * q] = pk.u;
            }
        }
    }
}

// ---------------- pool stage 1: partial sums, vectorized bf16x8 loads ---------
__global__ __launch_bounds__(256) void pool_stage1(
    const bf16* __restrict__ xb, const int* __restrict__ n_node,
    float* __restrict__ partialP)   // [N_GRAPH][POOL_PB][64]
{
    __shared__ float red[32][8][8];  // 8 KB
    int b = blockIdx.x;
    int g = b >> 3, sub = b & 7;
    int t = threadIdx.x;
    int start = 0;
    for (int j = 0; j < g; j++) start += n_node[j];
    int cnt = n_node[g];
    int jbeg = (int)(((long long)cnt * sub) / POOL_PB);
    int jend = (int)(((long long)cnt * (sub + 1)) / POOL_PB);
    int rg = t >> 3, cc = t & 7;
    float acc[8];
#pragma unroll
    for (int k = 0; k < 8; k++) acc[k] = 0.f;
    for (int j = jbeg + rg; j < jend; j += 32) {
        bf16x8 v = *(const bf16x8*)&xb[(size_t)(start + j) * 64 + cc * 8];
#pragma unroll
        for (int k = 0; k < 8; k++) acc[k] += bf2f(v[k]);
    }
#pragma unroll
    for (int k = 0; k < 8; k++) red[rg][cc][k] = acc[k];
    __syncthreads();
    if (t < 64) {
        float s = 0.f;
#pragma unroll 8
        for (int r = 0; r < 32; r++) s += red[r][t >> 3][t & 7];
        partialP[((size_t)g * POOL_PB + sub) * 64 + t] = s;
    }
}

// ---------------- pool stage 2: reduce partials + mean + decoder GEMV ---------
__global__ __launch_bounds__(64) void pool_stage2(
    const float* __restrict__ partialP, const int* __restrict__ n_node,
    const float* __restrict__ Wg, const float* __restrict__ bg,
    float* __restrict__ out)
{
    __shared__ float pd[64];
    int g = blockIdx.x;
    int t = threadIdx.x;
    float s = 0.f;
#pragma unroll
    for (int p = 0; p < POOL_PB; p++) s += partialP[((size_t)g * POOL_PB + p) * 64 + t];
    int cnt = n_node[g];
    pd[t] = s / fmaxf((float)cnt, 1.f);
    __syncthreads();
    if (t < OUT_G) {
        float v = bg[t];
#pragma unroll 16
        for (int dd = 0; dd < 64; dd++) v += pd[dd] * Wg[dd * OUT_G + t];
        out[g * OUT_G + t] = v;
    }
}

extern "C" void kernel_launch(void* const* d_in, const int* in_sizes, int n_in,
                              void* d_out, int out_size, void* d_ws, size_t ws_size,
                              hipStream_t stream) {
    const float* nodes    = (const float*)d_in[0];
    const int*   senders  = (const int*)d_in[1];
    const int*   receivers= (const int*)d_in[2];
    const int*   n_node   = (const int*)d_in[3];
    const float* W_embed  = (const float*)d_in[4];
    const float* b_embed  = (const float*)d_in[5];
    const float* W_mlp0   = (const float*)d_in[6];
    const float* b_mlp0   = (const float*)d_in[7];
    const float* W_mlp1   = (const float*)d_in[8];
    const float* b_mlp1   = (const float*)d_in[9];
    const float* ln_scale = (const float*)d_in[10];
    const float* ln_bias  = (const float*)d_in[11];
    const float* W_glob   = (const float*)d_in[12];
    const float* b_glob   = (const float*)d_in[13];
    float* out = (float*)d_out;

    // workspace layout (16B-aligned pieces)
    char* ws = (char*)d_ws;
    bf16*  xb     = (bf16*)ws;    ws += (size_t)N_NODES * 64 * 2;        // 12.8 MB
    unsigned char* h8 = (unsigned char*)ws; ws += (size_t)(N_NODES + 1) * 64; // 6.4 MB + zero row
    unsigned int* histS_g = (unsigned int*)ws; ws += (size_t)NSLICE * NCHUNK * CHUNKW * 4; // 12.8 MB
    unsigned int* histR_g = (unsigned int*)ws; ws += (size_t)NSLICE * NCHUNK * CHUNKW * 4; // 12.8 MB
    float* inv_s  = (float*)ws;   ws += (size_t)N_NODES * 4;
    float* inv_r  = (float*)ws;   ws += (size_t)N_NODES * 4;
    int*   cntPad = (int*)ws;     ws += (size_t)N_NODES * 4;
    int*   cntReal= (int*)ws;     ws += (size_t)N_NODES * 4;
    int*   row_ptr= (int*)ws;     ws += (size_t)(N_NODES + 4) * 4;
    int*   col    = (int*)ws;     ws += (size_t)COL_CAP * 4;             // 9.2 MB
    int*   partial= (int*)ws;     ws += 256 * 4;
    bf16*  wfrag  = (bf16*)ws;    ws += 8192 * 2;
    float* partialP = (float*)ws; ws += (size_t)N_GRAPH * POOL_PB * 64 * 4;

    // blockoffR (u8[NSLICE][N_NODES] = 12.8 MB) aliases xb (dead until embed)
    unsigned char* blockoffR = (unsigned char*)xb;

    const int nblk_scan = (N_NODES + 1023) / 1024;  // 98

    // ---- CSR build (no global atomics), padded rows ----
    csr_hist_both<<<2 * NSLICE * NCHUNK, 512, 0, stream>>>(receivers, senders, histR_g, histS_g);
    csr_scan_blocks<<<(NCHUNK * CHUNKW + 255) / 256, 256, 0, stream>>>(
        histR_g, histS_g, blockoffR, cntPad, cntReal, inv_r, inv_s);
    scan_blocksum<<<nblk_scan, 256, 0, stream>>>(cntPad, partial);
    scan_partials_par<<<1, 128, 0, stream>>>(partial, nblk_scan);
    scan_final<<<nblk_scan, 256, 0, stream>>>(cntPad, cntReal, partial, row_ptr, col);
    csr_scatter<<<NSLICE * NCHUNK, 512, 0, stream>>>(senders, receivers, row_ptr, blockoffR, col);

    // ---- embed (after CSR temporaries are dead) ----
    embed_kernel<<<(N_NODES * 8 + 255) / 256, 256, 0, stream>>>(nodes, W_embed, b_embed, xb, h8);
    wfrag_kernel<<<32, 256, 0, stream>>>(W_mlp0, W_mlp1, wfrag);

    for (int step = 0; step < N_STEPS; ++step) {
        mlp_mfma<<<1563, 256, 0, stream>>>(xb, h8, wfrag, b_mlp0, b_mlp1, inv_s);
        agg_ln_kernel<<<4096, 256, 0, stream>>>(h8, xb, row_ptr, col, inv_r, ln_scale, ln_bias);
    }

    pool_stage1<<<N_GRAPH * POOL_PB, 256, 0, stream>>>(xb, n_node, partialP);
    pool_stage2<<<N_GRAPH, 64, 0, stream>>>(partialP, n_node, W_glob, b_glob, out);
}

// Round 15
// 332.514 us; speedup vs baseline: 1.2773x; 1.0125x over previous
//
#include <hip/hip_runtime.h>
#include <hip/hip_bf16.h>
#include <hip/hip_fp8.h>

#define N_NODES 100000
#define N_EDGES 1600000
#define LATENT 64
#define N_GRAPH 100
#define OUT_G 16
#define N_STEPS 3

// CSR-build geometry (u8-packed histograms: 4 node-counts per u32 word)
#define NCHUNK 2
#define CHUNKN 50000            // nodes per chunk
#define CHUNKW 12500            // packed u8x4 words per chunk (50 KB LDS)
#define NSLICE 128
#define SLICE_E 12500           // edges per slice (128*12500 = 1.6M)

#define POOL_PB 8               // stage-1 blocks per graph
#define COL_CAP (N_EDGES + 7 * N_NODES + 64)   // padded CSR capacity

using bf16 = __hip_bfloat16;
using bf16x8 = __attribute__((ext_vector_type(8))) short;
using f32x4  = __attribute__((ext_vector_type(4))) float;

__device__ __forceinline__ float blo(unsigned int u) {
    union { unsigned int i; float f; } v; v.i = u << 16; return v.f;
}
__device__ __forceinline__ float bhi(unsigned int u) {
    union { unsigned int i; float f; } v; v.i = u & 0xffff0000u; return v.f;
}
__device__ __forceinline__ float bf2f(short s) {
    union { unsigned int i; float f; } v; v.i = ((unsigned int)(unsigned short)s) << 16; return v.f;
}
// 4 packed fp8 e4m3 -> 4 floats (native cvt on gfx950)
__device__ __forceinline__ float4 fp8x4(unsigned int u) {
    union { unsigned int w; __hip_fp8_storage_t b[4]; } c; c.w = u;
    __hip_fp8_e4m3 t0, t1, t2, t3;
    t0.__x = c.b[0]; t1.__x = c.b[1]; t2.__x = c.b[2]; t3.__x = c.b[3];
    return make_float4((float)t0, (float)t1, (float)t2, (float)t3);
}

// ------- K1: per-(chunk,slice) u8-packed LDS histogram; int4 edge loads -------
__global__ __launch_bounds__(512) void csr_hist_both(
    const int* __restrict__ receivers, const int* __restrict__ senders,
    unsigned int* __restrict__ histR_g, unsigned int* __restrict__ histS_g)
{
    __shared__ unsigned int hist[CHUNKW];   // 50 KB, u8 x4 per word
    int b = blockIdx.x;
    int isS = (b >= NSLICE * NCHUNK);
    int bb = b - isS * NSLICE * NCHUNK;
    const int* idx = isS ? senders : receivers;
    unsigned int* outg = (isS ? histS_g : histR_g) + (size_t)bb * CHUNKW;
    int c = bb & (NCHUNK - 1), s = bb >> 1;
    int t = threadIdx.x;
    for (int w = t; w < CHUNKW; w += 512) hist[w] = 0;
    __syncthreads();
    int base4 = s * (SLICE_E / 4);          // slice base in int4 units (12500%4==0)
    int lo = c * CHUNKN;
    const int4* idx4 = (const int4*)idx;
    for (int e4 = base4 + t; e4 < base4 + SLICE_E / 4; e4 += 512) {
        int4 v = idx4[e4];
        unsigned int r0 = (unsigned int)(v.x - lo);
        unsigned int r1 = (unsigned int)(v.y - lo);
        unsigned int r2 = (unsigned int)(v.z - lo);
        unsigned int r3 = (unsigned int)(v.w - lo);
        if (r0 < CHUNKN) atomicAdd(&hist[r0 >> 2], 1u << ((r0 & 3) * 8));
        if (r1 < CHUNKN) atomicAdd(&hist[r1 >> 2], 1u << ((r1 & 3) * 8));
        if (r2 < CHUNKN) atomicAdd(&hist[r2 >> 2], 1u << ((r2 & 3) * 8));
        if (r3 < CHUNKN) atomicAdd(&hist[r3 >> 2], 1u << ((r3 & 3) * 8));
    }
    __syncthreads();
    for (int w = t; w < CHUNKW; w += 512) outg[w] = hist[w];
}

// ------ K2: scan slice-partials -> u8 offsets + padded cnt + real cnt + inv ---
__global__ __launch_bounds__(256) void csr_scan_blocks(
    const unsigned int* __restrict__ histR_g, const unsigned int* __restrict__ histS_g,
    unsigned char* __restrict__ blockoffR, int* __restrict__ cntPad,
    int* __restrict__ cntReal, float* __restrict__ inv_r, float* __restrict__ inv_s)
{
    int tid = blockIdx.x * blockDim.x + threadIdx.x;
    if (tid >= NCHUNK * CHUNKW) return;
    int c = tid / CHUNKW, w = tid - c * CHUNKW;
    int node = c * CHUNKN + 4 * w;
    unsigned int r0 = 0, r1 = 0, r2 = 0, r3 = 0;
#pragma unroll 8
    for (int s = 0; s < NSLICE; s++) {
        unsigned int v = histR_g[(size_t)(s * NCHUNK + c) * CHUNKW + w];
        *(unsigned int*)&blockoffR[(size_t)s * N_NODES + node] =
            r0 | (r1 << 8) | (r2 << 16) | (r3 << 24);
        r0 += v & 0xffu; r1 += (v >> 8) & 0xffu;
        r2 += (v >> 16) & 0xffu; r3 += (v >> 24) & 0xffu;
    }
    ((int4*)cntReal)[node >> 2] = make_int4((int)r0, (int)r1, (int)r2, (int)r3);
    ((int4*)cntPad)[node >> 2] = make_int4(
        (int)((r0 + 7u) & ~7u), (int)((r1 + 7u) & ~7u),
        (int)((r2 + 7u) & ~7u), (int)((r3 + 7u) & ~7u));
    ((float4*)inv_r)[node >> 2] = make_float4(
        rsqrtf((float)(r0 + 1)), rsqrtf((float)(r1 + 1)),
        rsqrtf((float)(r2 + 1)), rsqrtf((float)(r3 + 1)));
    r0 = r1 = r2 = r3 = 0;
#pragma unroll 8
    for (int s = 0; s < NSLICE; s++) {
        unsigned int v = histS_g[(size_t)(s * NCHUNK + c) * CHUNKW + w];
        r0 += v & 0xffu; r1 += (v >> 8) & 0xffu;
        r2 += (v >> 16) & 0xffu; r3 += (v >> 24) & 0xffu;
    }
    ((float4*)inv_s)[node >> 2] = make_float4(
        rsqrtf((float)(r0 + 1)), rsqrtf((float)(r1 + 1)),
        rsqrtf((float)(r2 + 1)), rsqrtf((float)(r3 + 1)));
}

// ---------------- exclusive scan of padded counts -> row_ptr ----------------
__global__ __launch_bounds__(256) void scan_blocksum(
    const int* __restrict__ cnt, int* __restrict__ partial)
{
    __shared__ int sred[256];
    int b = blockIdx.x, t = threadIdx.x;
    int base = b * 1024 + t * 4;
    int s = 0;
#pragma unroll
    for (int j = 0; j < 4; j++) {
        int i = base + j;
        s += (i < N_NODES) ? cnt[i] : 0;
    }
    sred[t] = s;
    __syncthreads();
    for (int off = 128; off > 0; off >>= 1) {
        if (t < off) sred[t] += sred[t + off];
        __syncthreads();
    }
    if (t == 0) partial[b] = sred[0];
}

__global__ __launch_bounds__(128) void scan_partials_par(int* partial, int nblk)
{
    __shared__ int lds[128];
    int t = threadIdx.x;
    int v = (t < nblk) ? partial[t] : 0;
    lds[t] = v;
    __syncthreads();
    for (int off = 1; off < 128; off <<= 1) {
        int add = (t >= off) ? lds[t - off] : 0;
        __syncthreads();
        lds[t] += add;
        __syncthreads();
    }
    if (t < nblk) partial[t] = lds[t] - v;   // exclusive
}

// scan_final also writes the pad slots of col (zero-row index N_NODES)
__global__ __launch_bounds__(256) void scan_final(
    const int* __restrict__ cnt, const int* __restrict__ cntReal,
    const int* __restrict__ partial, int* __restrict__ row_ptr,
    int* __restrict__ col)
{
    __shared__ int lds[256];
    int b = blockIdx.x, t = threadIdx.x;
    int base = b * 1024 + t * 4;
    int v[4]; int s = 0;
#pragma unroll
    for (int j = 0; j < 4; j++) {
        int i = base + j;
        v[j] = (i < N_NODES) ? cnt[i] : 0;
        s += v[j];
    }
    lds[t] = s;
    __syncthreads();
    for (int off = 1; off < 256; off <<= 1) {
        int add = (t >= off) ? lds[t - off] : 0;
        __syncthreads();
        lds[t] += add;
        __syncthreads();
    }
    int run = lds[t] - s + partial[b];
#pragma unroll
    for (int j = 0; j < 4; j++) {
        int i = base + j;
        if (i < N_NODES) {
            row_ptr[i] = run;
            int real = cntReal[i];
            for (int k = real; k < v[j]; k++) col[run + k] = N_NODES;
            run += v[j];
            if (i == N_NODES - 1) row_ptr[N_NODES] = run;
        }
    }
}

// ------- K3: scatter with u8-packed LDS local ranks; int4 edge loads ----------
__global__ __launch_bounds__(512) void csr_scatter(
    const int* __restrict__ senders, const int* __restrict__ receivers,
    const int* __restrict__ row_ptr, const unsigned char* __restrict__ blockoffR,
    int* __restrict__ col)
{
    __shared__ unsigned int lrank[CHUNKW];   // 50 KB, u8 x4 per word
    int c = blockIdx.x & (NCHUNK - 1), s = blockIdx.x >> 1;
    int t = threadIdx.x;
    for (int w = t; w < CHUNKW; w += 512) lrank[w] = 0;
    __syncthreads();
    int base4 = s * (SLICE_E / 4);
    int lo = c * CHUNKN;
    const unsigned char* boff = blockoffR + (size_t)s * N_NODES;
    const int4* recv4 = (const int4*)receivers;
    const int4* send4 = (const int4*)senders;
    for (int e4 = base4 + t; e4 < base4 + SLICE_E / 4; e4 += 512) {
        int4 rv = recv4[e4];
        int4 sv = send4[e4];
        int rr[4] = {rv.x, rv.y, rv.z, rv.w};
        int ss[4] = {sv.x, sv.y, sv.z, sv.w};
#pragma unroll
        for (int j = 0; j < 4; j++) {
            unsigned int rl = (unsigned int)(rr[j] - lo);
            if (rl < CHUNKN) {
                unsigned int sh = (rl & 3) * 8;
                unsigned int old = atomicAdd(&lrank[rl >> 2], 1u << sh);
                unsigned int lr = (old >> sh) & 0xffu;
                col[row_ptr[rr[j]] + (int)boff[rr[j]] + (int)lr] = ss[j];
            }
        }
    }
}

// ---------------- embed: xb = bf16(nodes @ W_embed + b_embed) + zero row ------
__global__ __launch_bounds__(256) void embed_kernel(
    const float* __restrict__ nodes, const float* __restrict__ We,
    const float* __restrict__ be, bf16* __restrict__ xb, unsigned char* __restrict__ h8)
{
    int tid = blockIdx.x * blockDim.x + threadIdx.x;   // (node, col-chunk of 8)
    if (tid < 4) {   // zero row h8[N_NODES] for padded-CSR gathers
        uint4 z = {};
        *(uint4*)&h8[(size_t)N_NODES * 64 + tid * 16] = z;
    }
    if (tid >= N_NODES * 8) return;
    int i = tid >> 3, cc = tid & 7;
    float n0 = nodes[i * 3 + 0], n1 = nodes[i * 3 + 1], n2 = nodes[i * 3 + 2];
    union { bf16x8 v; bf16 h[8]; } pk;
#pragma unroll
    for (int k = 0; k < 8; k++) {
        int d = cc * 8 + k;
        float acc = be[d] + n0 * We[0 * 64 + d] + n1 * We[1 * 64 + d] + n2 * We[2 * 64 + d];
        pk.h[k] = __float2bfloat16(acc);
    }
    *(bf16x8*)&xb[(size_t)i * 64 + cc * 8] = pk.v;
}

// ---------------- W fragment pre-pack (f32 -> bf16, MFMA frag order) ----------
__global__ __launch_bounds__(256) void wfrag_kernel(
    const float* __restrict__ W0, const float* __restrict__ W1,
    bf16* __restrict__ frags)
{
    int tid = blockIdx.x * blockDim.x + threadIdx.x;
    if (tid >= 8192) return;
    int j    = tid & 7;
    int lane = (tid >> 3) & 63;
    int c    = (tid >> 9) & 1;
    int nt   = (tid >> 10) & 3;
    int L    = (tid >> 12) & 1;
    int g = lane >> 4, q = lane & 15;
    int k = c * 32 + g * 8 + j;
    int colIdx = nt * 16 + q;
    const float* W = L ? W1 : W0;
    frags[tid] = __float2bfloat16(W[k * 64 + colIdx]);
}

// ------ MFMA 2-layer MLP (+ inv_sqrt_s epilogue), bf16 compute, fp8 h out -----
__global__ __launch_bounds__(256) void mlp_mfma(
    const bf16* __restrict__ xb, unsigned char* __restrict__ h8,
    const bf16* __restrict__ wfrag,
    const float* __restrict__ b0, const float* __restrict__ b1,
    const float* __restrict__ inv_s)
{
    __shared__ char lds_raw[4][2048];
    int t = threadIdx.x;
    int w = t >> 6, lane = t & 63;
    int g = lane >> 4, q = lane & 15;
    char* myLds = lds_raw[w];

    bf16x8 wf[2][4][2];
#pragma unroll
    for (int L = 0; L < 2; L++)
#pragma unroll
        for (int nt = 0; nt < 4; nt++)
#pragma unroll
            for (int c = 0; c < 2; c++)
                wf[L][nt][c] = *(const bf16x8*)&wfrag[((((L * 4 + nt) * 2 + c) * 64) + lane) * 8];

    float bias0[4], bias1[4];
#pragma unroll
    for (int nt = 0; nt < 4; nt++) {
        bias0[nt] = b0[nt * 16 + q];
        bias1[nt] = b1[nt * 16 + q];
    }

    const int NTILES = N_NODES / 16;  // 6250
    for (int tile = blockIdx.x * 4 + w; tile < NTILES; tile += gridDim.x * 4) {
        int nodeBase = tile * 16;

        bf16x8 a0[2];
#pragma unroll
        for (int c = 0; c < 2; c++)
            a0[c] = *(const bf16x8*)&xb[(size_t)(nodeBase + q) * 64 + c * 32 + g * 8];

        f32x4 acc[4];
#pragma unroll
        for (int nt = 0; nt < 4; nt++) {
            acc[nt] = (f32x4){bias0[nt], bias0[nt], bias0[nt], bias0[nt]};
            acc[nt] = __builtin_amdgcn_mfma_f32_16x16x32_bf16(a0[0], wf[0][nt][0], acc[nt], 0, 0, 0);
            acc[nt] = __builtin_amdgcn_mfma_f32_16x16x32_bf16(a0[1], wf[0][nt][1], acc[nt], 0, 0, 0);
        }
#pragma unroll
        for (int nt = 0; nt < 4; nt++)
#pragma unroll
            for (int r = 0; r < 4; r++) {
                float v = fmaxf(acc[nt][r], 0.f);
                int node = g * 4 + r;
                int byte = ((node * 128 + (nt * 16 + q) * 2)) ^ ((node & 7) << 4);
                *(bf16*)(myLds + byte) = __float2bfloat16(v);
            }
        bf16x8 a1[2];
#pragma unroll
        for (int c = 0; c < 2; c++) {
            int byte = (q * 128 + c * 64 + g * 16) ^ ((q & 7) << 4);
            a1[c] = *(const bf16x8*)(myLds + byte);
        }

        f32x4 acc1[4];
#pragma unroll
        for (int nt = 0; nt < 4; nt++) {
            acc1[nt] = (f32x4){bias1[nt], bias1[nt], bias1[nt], bias1[nt]};
            acc1[nt] = __builtin_amdgcn_mfma_f32_16x16x32_bf16(a1[0], wf[1][nt][0], acc1[nt], 0, 0, 0);
            acc1[nt] = __builtin_amdgcn_mfma_f32_16x16x32_bf16(a1[1], wf[1][nt][1], acc1[nt], 0, 0, 0);
        }
        float is[4];
#pragma unroll
        for (int r = 0; r < 4; r++) is[r] = inv_s[nodeBase + g * 4 + r];
#pragma unroll
        for (int nt = 0; nt < 4; nt++)
#pragma unroll
            for (int r = 0; r < 4; r++) {
                float v = fmaxf(acc1[nt][r], 0.f) * is[r];
                int node = g * 4 + r;
                int byte = ((node * 128 + (nt * 16 + q) * 2)) ^ ((node & 7) << 4);
                *(bf16*)(myLds + byte) = __float2bfloat16(v);
            }
        // linear read-back, convert to fp8, single 16B store per lane
        union { uint4 u4; unsigned char b[16]; } pk8;
#pragma unroll
        for (int half = 0; half < 2; half++) {
            int byteL = lane * 32 + half * 16;
            int node = byteL >> 7;
            bf16x8 v = *(const bf16x8*)(myLds + (byteL ^ ((node & 7) << 4)));
#pragma unroll
            for (int k = 0; k < 8; k++) {
                __hip_fp8_e4m3 f8(bf2f(v[k]));
                pk8.b[half * 8 + k] = f8.__x;
            }
        }
        *(uint4*)&h8[(size_t)nodeBase * 64 + lane * 16] = pk8.u4;
    }
}

// --- gather-aggregate: fp8 h, 4 interleaved rows per wave, padded rows, LN ----
__global__ __launch_bounds__(256) void agg_ln_kernel(
    const unsigned char* __restrict__ h8, bf16* __restrict__ xb,
    const int* __restrict__ row_ptr, const int* __restrict__ col,
    const float* __restrict__ inv_r,
    const float* __restrict__ ln_scale, const float* __restrict__ ln_bias)
{
    int t = threadIdx.x;
    int lane = t & 63;
    int sub = lane >> 4;          // edge-slot 0..3
    int q = lane & 15;            // this lane covers columns 4q..4q+3
    float4 lnsv = *(const float4*)&ln_scale[4 * q];
    float4 lnbv = *(const float4*)&ln_bias[4 * q];
    int gw = __builtin_amdgcn_readfirstlane((blockIdx.x * blockDim.x + t) >> 6);
    int nwaves = (gridDim.x * blockDim.x) >> 6;
    for (int i0 = gw; i0 < N_NODES; i0 += 4 * nwaves) {
        int   iR[4];
        bool  has[4];
        int   eC[4], endC[4];
        int2  ci[4];
        float A[4][4];
#pragma unroll
        for (int k = 0; k < 4; k++) {
            iR[k] = i0 + k * nwaves;
            has[k] = (iR[k] < N_NODES);
            int ii = has[k] ? iR[k] : 0;
            eC[k]   = has[k] ? row_ptr[ii]     : 0;
            endC[k] = has[k] ? row_ptr[ii + 1] : 0;
#pragma unroll
            for (int j = 0; j < 4; j++) A[k][j] = 0.f;
            // self edge (inv_s already folded into h); counted once via sub==0
            unsigned int su = has[k] ? *(const unsigned int*)&h8[(size_t)iR[k] * 64 + 4 * q] : 0u;
            if (sub == 0) {
                float4 s4 = fp8x4(su);
                A[k][0] = s4.x; A[k][1] = s4.y; A[k][2] = s4.z; A[k][3] = s4.w;
            }
            ci[k] = (eC[k] < endC[k]) ? *(const int2*)&col[eC[k] + 2 * sub]
                                      : make_int2(N_NODES, N_NODES);
        }
        bool more = true;
        while (more) {            // all conditions wave-uniform
            more = false;
#pragma unroll
            for (int k = 0; k < 4; k++) {
                if (eC[k] < endC[k]) {
                    int ne = eC[k] + 8;
                    int2 cn = (ne < endC[k]) ? *(const int2*)&col[ne + 2 * sub]
                                             : make_int2(N_NODES, N_NODES);
                    unsigned int u0 = *(const unsigned int*)&h8[(size_t)ci[k].x * 64 + 4 * q];
                    unsigned int u1 = *(const unsigned int*)&h8[(size_t)ci[k].y * 64 + 4 * q];
                    float4 f0 = fp8x4(u0);
                    float4 f1 = fp8x4(u1);
                    A[k][0] += f0.x + f1.x; A[k][1] += f0.y + f1.y;
                    A[k][2] += f0.z + f1.z; A[k][3] += f0.w + f1.w;
                    ci[k] = cn; eC[k] = ne;
                    if (ne < endC[k]) more = true;
                }
            }
        }
        // ---- per-row: merge slots, LN, store ----
#pragma unroll
        for (int k = 0; k < 4; k++) {
            if (has[k]) {
                float a0 = A[k][0], a1 = A[k][1], a2 = A[k][2], a3 = A[k][3];
                a0 += __shfl_xor(a0, 16); a0 += __shfl_xor(a0, 32);
                a1 += __shfl_xor(a1, 16); a1 += __shfl_xor(a1, 32);
                a2 += __shfl_xor(a2, 16); a2 += __shfl_xor(a2, 32);
                a3 += __shfl_xor(a3, 16); a3 += __shfl_xor(a3, 32);
                float ir = inv_r[iR[k]];
                uint2 xu = *(const uint2*)&xb[(size_t)iR[k] * 64 + 4 * q];
                float y0 = a0 * ir + blo(xu.x);
                float y1 = a1 * ir + bhi(xu.x);
                float y2 = a2 * ir + blo(xu.y);
                float y3 = a3 * ir + bhi(xu.y);
                float sum = (y0 + y1) + (y2 + y3);
#pragma unroll
                for (int m = 1; m < 16; m <<= 1) sum += __shfl_xor(sum, m);
                float mu = sum * (1.f / 64.f);
                float d0 = y0 - mu, d1 = y1 - mu, d2 = y2 - mu, d3 = y3 - mu;
                float vs = (d0 * d0 + d1 * d1) + (d2 * d2 + d3 * d3);
#pragma unroll
                for (int m = 1; m < 16; m <<= 1) vs += __shfl_xor(vs, m);
                float rr = rsqrtf(vs * (1.f / 64.f) + 1e-6f);
                if (sub == 0) {
                    union { uint2 u; bf16 h4[4]; } pk;
                    pk.h4[0] = __float2bfloat16(d0 * rr * lnsv.x + lnbv.x);
                    pk.h4[1] = __float2bfloat16(d1 * rr * lnsv.y + lnbv.y);
                    pk.h4[2] = __float2bfloat16(d2 * rr * lnsv.z + lnbv.z);
                    pk.h4[3] = __float2bfloat16(d3 * rr * lnsv.w + lnbv.w);
                    *(uint2*)&xb[(size_t)iR[k] * 64 + 4 * q] = pk.u;
                }
            }
        }
    }
}

// ---------------- pool stage 1: partial sums, vectorized bf16x8 loads ---------
__global__ __launch_bounds__(256) void pool_stage1(
    const bf16* __restrict__ xb, const int* __restrict__ n_node,
    float* __restrict__ partialP)   // [N_GRAPH][POOL_PB][64]
{
    __shared__ float red[32][8][8];  // 8 KB
    int b = blockIdx.x;
    int g = b >> 3, sub = b & 7;
    int t = threadIdx.x;
    int start = 0;
    for (int j = 0; j < g; j++) start += n_node[j];
    int cnt = n_node[g];
    int jbeg = (int)(((long long)cnt * sub) / POOL_PB);
    int jend = (int)(((long long)cnt * (sub + 1)) / POOL_PB);
    int rg = t >> 3, cc = t & 7;
    float acc[8];
#pragma unroll
    for (int k = 0; k < 8; k++) acc[k] = 0.f;
    for (int j = jbeg + rg; j < jend; j += 32) {
        bf16x8 v = *(const bf16x8*)&xb[(size_t)(start + j) * 64 + cc * 8];
#pragma unroll
        for (int k = 0; k < 8; k++) acc[k] += bf2f(v[k]);
    }
#pragma unroll
    for (int k = 0; k < 8; k++) red[rg][cc][k] = acc[k];
    __syncthreads();
    if (t < 64) {
        float s = 0.f;
#pragma unroll 8
        for (int r = 0; r < 32; r++) s += red[r][t >> 3][t & 7];
        partialP[((size_t)g * POOL_PB + sub) * 64 + t] = s;
    }
}

// ---------------- pool stage 2: reduce partials + mean + decoder GEMV ---------
__global__ __launch_bounds__(64) void pool_stage2(
    const float* __restrict__ partialP, const int* __restrict__ n_node,
    const float* __restrict__ Wg, const float* __restrict__ bg,
    float* __restrict__ out)
{
    __shared__ float pd[64];
    int g = blockIdx.x;
    int t = threadIdx.x;
    float s = 0.f;
#pragma unroll
    for (int p = 0; p < POOL_PB; p++) s += partialP[((size_t)g * POOL_PB + p) * 64 + t];
    int cnt = n_node[g];
    pd[t] = s / fmaxf((float)cnt, 1.f);
    __syncthreads();
    if (t < OUT_G) {
        float v = bg[t];
#pragma unroll 16
        for (int dd = 0; dd < 64; dd++) v += pd[dd] * Wg[dd * OUT_G + t];
        out[g * OUT_G + t] = v;
    }
}

extern "C" void kernel_launch(void* const* d_in, const int* in_sizes, int n_in,
                              void* d_out, int out_size, void* d_ws, size_t ws_size,
                              hipStream_t stream) {
    const float* nodes    = (const float*)d_in[0];
    const int*   senders  = (const int*)d_in[1];
    const int*   receivers= (const int*)d_in[2];
    const int*   n_node   = (const int*)d_in[3];
    const float* W_embed  = (const float*)d_in[4];
    const float* b_embed  = (const float*)d_in[5];
    const float* W_mlp0   = (const float*)d_in[6];
    const float* b_mlp0   = (const float*)d_in[7];
    const float* W_mlp1   = (const float*)d_in[8];
    const float* b_mlp1   = (const float*)d_in[9];
    const float* ln_scale = (const float*)d_in[10];
    const float* ln_bias  = (const float*)d_in[11];
    const float* W_glob   = (const float*)d_in[12];
    const float* b_glob   = (const float*)d_in[13];
    float* out = (float*)d_out;

    // workspace layout (16B-aligned pieces)
    char* ws = (char*)d_ws;
    bf16*  xb     = (bf16*)ws;    ws += (size_t)N_NODES * 64 * 2;        // 12.8 MB
    unsigned char* h8 = (unsigned char*)ws; ws += (size_t)(N_NODES + 1) * 64; // 6.4 MB + zero row
    unsigned int* histS_g = (unsigned int*)ws; ws += (size_t)NSLICE * NCHUNK * CHUNKW * 4; // 12.8 MB
    unsigned int* histR_g = (unsigned int*)ws; ws += (size_t)NSLICE * NCHUNK * CHUNKW * 4; // 12.8 MB
    float* inv_s  = (float*)ws;   ws += (size_t)N_NODES * 4;
    float* inv_r  = (float*)ws;   ws += (size_t)N_NODES * 4;
    int*   cntPad = (int*)ws;     ws += (size_t)N_NODES * 4;
    int*   cntReal= (int*)ws;     ws += (size_t)N_NODES * 4;
    int*   row_ptr= (int*)ws;     ws += (size_t)(N_NODES + 4) * 4;
    int*   col    = (int*)ws;     ws += (size_t)COL_CAP * 4;             // 9.2 MB
    int*   partial= (int*)ws;     ws += 256 * 4;
    bf16*  wfrag  = (bf16*)ws;    ws += 8192 * 2;
    float* partialP = (float*)ws; ws += (size_t)N_GRAPH * POOL_PB * 64 * 4;

    // blockoffR (u8[NSLICE][N_NODES] = 12.8 MB) aliases xb (dead until embed)
    unsigned char* blockoffR = (unsigned char*)xb;

    const int nblk_scan = (N_NODES + 1023) / 1024;  // 98

    // ---- CSR build (no global atomics), padded rows ----
    csr_hist_both<<<2 * NSLICE * NCHUNK, 512, 0, stream>>>(receivers, senders, histR_g, histS_g);
    csr_scan_blocks<<<(NCHUNK * CHUNKW + 255) / 256, 256, 0, stream>>>(
        histR_g, histS_g, blockoffR, cntPad, cntReal, inv_r, inv_s);
    scan_blocksum<<<nblk_scan, 256, 0, stream>>>(cntPad, partial);
    scan_partials_par<<<1, 128, 0, stream>>>(partial, nblk_scan);
    scan_final<<<nblk_scan, 256, 0, stream>>>(cntPad, cntReal, partial, row_ptr, col);
    csr_scatter<<<NSLICE * NCHUNK, 512, 0, stream>>>(senders, receivers, row_ptr, blockoffR, col);

    // ---- embed (after CSR temporaries are dead) ----
    embed_kernel<<<(N_NODES * 8 + 255) / 256, 256, 0, stream>>>(nodes, W_embed, b_embed, xb, h8);
    wfrag_kernel<<<32, 256, 0, stream>>>(W_mlp0, W_mlp1, wfrag);

    for (int step = 0; step < N_STEPS; ++step) {
        mlp_mfma<<<1563, 256, 0, stream>>>(xb, h8, wfrag, b_mlp0, b_mlp1, inv_s);
        agg_ln_kernel<<<4096, 256, 0, stream>>>(h8, xb, row_ptr, col, inv_r, ln_scale, ln_bias);
    }

    pool_stage1<<<N_GRAPH * POOL_PB, 256, 0, stream>>>(xb, n_node, partialP);
    pool_stage2<<<N_GRAPH, 64, 0, stream>>>(partialP, n_node, W_glob, b_glob, out);
}